// Round 6
// baseline (1007.071 us; speedup 1.0000x reference)
//
#include <hip/hip_runtime.h>
#include <stdint.h>

// InteractionModel: N=8192, D=512, T=12. All inputs/outputs fp32.
// R11: gemm_core re-tiled 128x128 -> 256x128 (wave tile 128x64, TM=8,TN=4,
//      32 MFMA/wave/K-step): halves barriers per FLOP, ds_read:MFMA ratio
//      12:32 (was 8:16), L3 panel traffic per output -33%. Counted-vmcnt
//      2-phase skeleton kept. LDS 48KB, launch_bounds(256,2).
//      Scores sub-grids XCD-chunked (each XCD owns 4 Q-panels -> L2-resident).
//      setprio kept (null on 2-phase but harmless; tile is bigger now).
// Workspace: 0 x1b, 8 x2b, 16 x4b | 24/32/40 x1t/x2t/x4t | 48 Wb |
//   52 Qs (4x8MB, F_a overlays Q_a) | 84 P0 (128MB) | 212 P1 (128MB)

#define DEV __device__ __forceinline__
typedef unsigned short u16;
typedef __bf16 bf16x8 __attribute__((ext_vector_type(8)));
typedef float f32x4 __attribute__((ext_vector_type(4)));

constexpr int NR = 8192;
constexpr int DDIM = 512;
constexpr int TOUT = 12;

DEV u16 f2b(float f) {
  uint32_t u = __builtin_bit_cast(uint32_t, f);
  u += 0x7fffu + ((u >> 16) & 1u);
  return (u16)(u >> 16);
}
DEV float b2f(u16 h) {
  uint32_t u = ((uint32_t)h) << 16;
  return __builtin_bit_cast(float, u);
}

// ---------------- LayerNorm: fp32 in -> bf16 out ----------------
__global__ __launch_bounds__(64) void ln_kernel(
    const float* __restrict__ xp, const float* __restrict__ xm,
    const float* __restrict__ xs, const float* __restrict__ g,
    const float* __restrict__ b, u16* __restrict__ o1, u16* __restrict__ o2,
    u16* __restrict__ o4) {
  int row = blockIdx.x;
  int which = blockIdx.y;
  const float* x = which == 0 ? xp : (which == 1 ? xm : xs);
  u16* o = which == 0 ? o1 : (which == 1 ? o2 : o4);
  int lane = threadIdx.x;
  const float4* xr = (const float4*)(x + (size_t)row * DDIM);
  float4 v0 = xr[lane * 2], v1 = xr[lane * 2 + 1];
  float vals[8] = {v0.x, v0.y, v0.z, v0.w, v1.x, v1.y, v1.z, v1.w};
  float s = 0.f, s2 = 0.f;
  for (int j = 0; j < 8; j++) { s += vals[j]; s2 += vals[j] * vals[j]; }
  for (int off = 1; off < 64; off <<= 1) {
    s += __shfl_xor(s, off);
    s2 += __shfl_xor(s2, off);
  }
  float m = s * (1.0f / DDIM);
  float var = s2 * (1.0f / DDIM) - m * m;
  var = fmaxf(var, 0.f);
  float rs = rsqrtf(var + 1e-6f);
  int d0 = lane * 8;
  u16 us[8];
  for (int j = 0; j < 8; j++)
    us[j] = f2b((vals[j] - m) * rs * g[d0 + j] + b[d0 + j]);
  uint4 pk;
  pk.x = (uint32_t)us[0] | ((uint32_t)us[1] << 16);
  pk.y = (uint32_t)us[2] | ((uint32_t)us[3] << 16);
  pk.z = (uint32_t)us[4] | ((uint32_t)us[5] << 16);
  pk.w = (uint32_t)us[6] | ((uint32_t)us[7] << 16);
  *(uint4*)(o + (size_t)row * DDIM + d0) = pk;
}

// ---------------- W fp32 -> bf16 ----------------
__global__ __launch_bounds__(256) void wconv_kernel(
    const float* __restrict__ W1, const float* __restrict__ W2,
    const float* __restrict__ W3, const float* __restrict__ W4,
    u16* __restrict__ Wb) {
  int wi = blockIdx.y;
  const float* W = wi == 0 ? W1 : (wi == 1 ? W2 : (wi == 2 ? W3 : W4));
  size_t base = ((size_t)blockIdx.x * 256 + threadIdx.x) * 8;
  const float4* src = (const float4*)(W + base);
  float4 a = src[0], c = src[1];
  float vals[8] = {a.x, a.y, a.z, a.w, c.x, c.y, c.z, c.w};
  u16 us[8];
  for (int j = 0; j < 8; j++) us[j] = f2b(vals[j]);
  uint4 pk;
  pk.x = (uint32_t)us[0] | ((uint32_t)us[1] << 16);
  pk.y = (uint32_t)us[2] | ((uint32_t)us[3] << 16);
  pk.z = (uint32_t)us[4] | ((uint32_t)us[5] << 16);
  pk.w = (uint32_t)us[6] | ((uint32_t)us[7] << 16);
  *(uint4*)(Wb + (size_t)wi * DDIM * DDIM + base) = pk;
}

// ---------------- bf16 transpose [8192][512] -> [512][8192] ----------------
__global__ __launch_bounds__(256) void transpose_kernel(
    const u16* __restrict__ s1, const u16* __restrict__ s2,
    const u16* __restrict__ s4, u16* __restrict__ t1, u16* __restrict__ t2,
    u16* __restrict__ t4) {
  constexpr int LD = 66;
  __shared__ u16 tile[64 * LD];
  int which = blockIdx.z;
  const u16* src = which == 0 ? s1 : (which == 1 ? s2 : s4);
  u16* dst = which == 0 ? t1 : (which == 1 ? t2 : t4);
  int c0 = blockIdx.x * 64;
  int r0 = blockIdx.y * 64;
  int tid = threadIdx.x;
  for (int c = tid; c < 512; c += 256) {
    int i = c >> 3, j8 = (c & 7) * 8;
    uint4 v = *(const uint4*)(src + (size_t)(r0 + i) * DDIM + c0 + j8);
    uint32_t* dw = (uint32_t*)&tile[i * LD + j8];
    dw[0] = v.x; dw[1] = v.y; dw[2] = v.z; dw[3] = v.w;
  }
  __syncthreads();
  for (int rep = 0; rep < 2; rep++) {
    int idx = rep * 256 + tid;
    int o = idx >> 3, j8 = (idx & 7) * 8;
    u16 us[8];
    for (int k = 0; k < 8; k++) us[k] = tile[(j8 + k) * LD + o];
    uint4 pk;
    pk.x = (uint32_t)us[0] | ((uint32_t)us[1] << 16);
    pk.y = (uint32_t)us[2] | ((uint32_t)us[3] << 16);
    pk.z = (uint32_t)us[4] | ((uint32_t)us[5] << 16);
    pk.w = (uint32_t)us[6] | ((uint32_t)us[7] << 16);
    *(uint4*)(dst + (size_t)(c0 + o) * NR + r0 + j8) = pk;
  }
}

// ---------------- shared bt-GEMM core (BM=256, BN=128, BK=32) --------------
// 4 waves in 2x2 grid, wave tile 128x64 (TM=8, TN=4, 32 MFMA/K-step).
// Double-buffered, counted vmcnt, hoisted staging pointers.
// LDS slot (row,s) holds global chunk (s-(row>>1))&3; reader uses
// s=(q+(r>>1))&3 -> bank-group (4r+s)%8 covers all 8 -> 2-way (free).
// MODE 0: out bf16 = acc + bias[col]   MODE 1: out bf16 = exp(acc - 48)
// lds: 24576 u16 (48 KB): buf b at b*12288 (A 8192 | B 4096).
template <int MODE>
DEV void gemm_core(const u16* __restrict__ A, const u16* __restrict__ B,
                   u16* __restrict__ C, const float* __restrict__ bias,
                   u16* lds, int K, int lda, int ldb, int ldc, int bx,
                   int by) {
  constexpr int TM = 8, TN = 4;
  int tid = threadIdx.x;
  int w = tid >> 6, lane = tid & 63;
  int q = lane >> 4, c16 = lane & 15;
  int n0 = bx * 128, m0 = by * 256;
  int wrow = (w >> 1) * 128, wcol = (w & 1) * 64;

  // staging: A 1024 chunks (256 rows x 4), B 512 chunks (128 x 4);
  // 6 wave-uniform calls x 64 lanes = 1536 chunks.
  const u16* gptr[6];
  int lof[6];  // u16 offset within a buffer (wave-uniform base)
#pragma unroll
  for (int j = 0; j < 6; j++) {
    int cb = j * 256 + w * 64;  // wave-uniform
    int c = cb + lane;
    bool isA = cb < 1024;  // uniform per wave (1024 % 64 == 0)
    int ci = isA ? c : c - 1024;
    int row = ci >> 2;
    int gch = ((ci & 3) - (row >> 1)) & 3;  // source chunk for this slot
    gptr[j] = isA ? (A + (size_t)(m0 + row) * lda + gch * 8)
                  : (B + (size_t)(n0 + row) * ldb + gch * 8);
    lof[j] = isA ? (cb * 8) : (8192 + (cb - 1024) * 8);
  }
  auto stageAll = [&](int buf) {
    int bo = buf * 12288;
#pragma unroll
    for (int j = 0; j < 6; j++) {
      __builtin_amdgcn_global_load_lds(
          (const __attribute__((address_space(1))) void*)gptr[j],
          (__attribute__((address_space(3))) void*)(lds + bo + lof[j]), 16, 0,
          0);
      gptr[j] += 32;  // next K-step (32 u16 = 64 B)
    }
  };

  f32x4 acc[TM][TN] = {};
  int nk = K >> 5;  // 16 for K=512
  stageAll(0);
  stageAll(1);  // 12 loads in flight per wave
  for (int ks = 0; ks < nk; ks++) {
    int cur = ks & 1;
    if (ks + 1 < nk)
      asm volatile("s_waitcnt vmcnt(6)" ::: "memory");
    else
      asm volatile("s_waitcnt vmcnt(0)" ::: "memory");
    __builtin_amdgcn_sched_barrier(0);
    __builtin_amdgcn_s_barrier();
    __builtin_amdgcn_sched_barrier(0);
    const u16* Asm = lds + cur * 12288;
    const u16* Bsm = Asm + 8192;
    bf16x8 af[TM], bfr[TN];
#pragma unroll
    for (int i = 0; i < TM; i++) {
      int r = wrow + i * 16 + c16;
      af[i] = *(const bf16x8*)&Asm[r * 32 + (((q + (r >> 1)) & 3) * 8)];
    }
#pragma unroll
    for (int n = 0; n < TN; n++) {
      int r = wcol + n * 16 + c16;
      bfr[n] = *(const bf16x8*)&Bsm[r * 32 + (((q + (r >> 1)) & 3) * 8)];
    }
    __builtin_amdgcn_s_setprio(1);
#pragma unroll
    for (int i = 0; i < TM; i++)
#pragma unroll
      for (int n = 0; n < TN; n++)
        acc[i][n] = __builtin_amdgcn_mfma_f32_16x16x32_bf16(af[i], bfr[n],
                                                            acc[i][n], 0, 0, 0);
    __builtin_amdgcn_s_setprio(0);
    asm volatile("s_waitcnt lgkmcnt(0)" ::: "memory");
    __builtin_amdgcn_sched_barrier(0);
    __builtin_amdgcn_s_barrier();
    __builtin_amdgcn_sched_barrier(0);
    if (ks + 2 < nk) stageAll(cur);  // refill the buffer just consumed
  }
  // ---- coalesced epilogue: two passes over col-halves of the 256x128 tile --
  // LDS viewed [256][64] u16 (16384 u16 < 24576 available).
  for (int h = 0; h < 2; h++) {
    __syncthreads();
    if ((w & 1) == h) {
      for (int i = 0; i < TM; i++) {
        for (int n = 0; n < TN; n++) {
          float bv = 0.f;
          if constexpr (MODE == 0) bv = bias[n0 + wcol + n * 16 + c16];
          for (int r = 0; r < 4; r++) {
            int rl = wrow + i * 16 + q * 4 + r;                // 0..255
            int cl = (n * 16 + c16) ^ ((rl & 7) << 3);         // swizzled col
            float v = acc[i][n][r];
            if constexpr (MODE == 0) v += bv;
            if constexpr (MODE == 1) v = __expf(v - 48.0f);
            lds[rl * 64 + cl] = f2b(v);
          }
        }
      }
    }
    __syncthreads();
    for (int rep = 0; rep < 8; rep++) {
      int idx = rep * 256 + tid;  // 0..2047 uint4s = 256 rows x 8 segs
      int row = idx >> 3, seg = idx & 7;
      uint4 vv = ((const uint4*)lds)[row * 8 + (seg ^ (row & 7))];
      *(uint4*)(C + (size_t)(m0 + row) * ldc + n0 + h * 64 + seg * 8) = vv;
    }
  }
}

// ---------------- PV body: F = (P V)/(l sqrt512) ----------
// BM=64, BN=128, BK=64; 512 blocks. Counted-vmcnt pipeline, hoisted
// pointers, setprio. lds: 24576 u16 (48 KB).
DEV void pv_body(const u16* __restrict__ A, const u16* __restrict__ B,
                 u16* lds, u16* __restrict__ C, int bx, int by) {
  constexpr int BM = 64, BN = 128, BK = 64;
  int tid = threadIdx.x, w = tid >> 6, lane = tid & 63;
  int q = lane >> 4, c16 = lane & 15;
  int n0 = bx * BN, m0 = by * BM;
  int wr = (w >> 1) * 32, wc = (w & 1) * 64;
  f32x4 acc[2][4] = {};
  f32x4 accl[2] = {};
  bf16x8 ones;
  for (int j = 0; j < 8; j++) ones[j] = (__bf16)1.0f;

  const u16* gptr[6];
  int lof0[6], lof1[6];
#pragma unroll
  for (int it = 0; it < 6; it++) {
    int cb = it * 256 + w * 64;  // wave-uniform
    int c = cb + lane;
    bool isA = cb < 512;  // uniform per wave
    int ci = isA ? c : c - 512;
    int row = ci >> 3;
    int koff = ((ci & 7) ^ (row & 7)) * 8;  // full 8-group swizzle
    gptr[it] = isA ? (A + (size_t)(m0 + row) * NR + koff)
                   : (B + (size_t)(n0 + row) * NR + koff);
    lof0[it] = isA ? (cb * 8) : (8192 + (cb - 512) * 8);
    lof1[it] = isA ? (4096 + cb * 8) : (16384 + (cb - 512) * 8);
  }
  auto stage = [&](int buf) {
#pragma unroll
    for (int it = 0; it < 6; it++) {
      int lo = buf ? lof1[it] : lof0[it];
      __builtin_amdgcn_global_load_lds(
          (const __attribute__((address_space(1))) void*)gptr[it],
          (__attribute__((address_space(3))) void*)(lds + lo), 16, 0, 0);
      gptr[it] += BK;  // next K-tile (64 u16 = 128 B)
    }
  };

  constexpr int KSTEPS = NR / BK;
  stage(0);
  stage(1);  // 12 loads in flight
  for (int ks = 0; ks < KSTEPS; ks++) {
    int cur = ks & 1;
    if (ks + 1 < KSTEPS)
      asm volatile("s_waitcnt vmcnt(6)" ::: "memory");
    else
      asm volatile("s_waitcnt vmcnt(0)" ::: "memory");
    __builtin_amdgcn_sched_barrier(0);
    __builtin_amdgcn_s_barrier();
    __builtin_amdgcn_sched_barrier(0);
    const u16* Asm = lds + cur * 4096;
    const u16* Bsm = lds + 8192 + cur * 8192;
#pragma unroll
    for (int kh = 0; kh < 2; kh++) {
      bf16x8 af[2], bfr[4];
      int cl = kh * 4 + q;
#pragma unroll
      for (int i = 0; i < 2; i++) {
        int r = wr + i * 16 + c16;
        af[i] = *(const bf16x8*)&Asm[r * BK + ((cl ^ (r & 7)) * 8)];
      }
#pragma unroll
      for (int n = 0; n < 4; n++) {
        int r = wc + n * 16 + c16;
        bfr[n] = *(const bf16x8*)&Bsm[r * BK + ((cl ^ (r & 7)) * 8)];
      }
      __builtin_amdgcn_s_setprio(1);
#pragma unroll
      for (int i = 0; i < 2; i++)
        accl[i] = __builtin_amdgcn_mfma_f32_16x16x32_bf16(af[i], ones, accl[i],
                                                          0, 0, 0);
#pragma unroll
      for (int i = 0; i < 2; i++)
#pragma unroll
        for (int n = 0; n < 4; n++)
          acc[i][n] = __builtin_amdgcn_mfma_f32_16x16x32_bf16(
              af[i], bfr[n], acc[i][n], 0, 0, 0);
      __builtin_amdgcn_s_setprio(0);
    }
    asm volatile("s_waitcnt lgkmcnt(0)" ::: "memory");
    __builtin_amdgcn_sched_barrier(0);
    __builtin_amdgcn_s_barrier();
    __builtin_amdgcn_sched_barrier(0);
    if (ks + 2 < KSTEPS) stage(cur);  // refill freed buffer
  }
  for (int i = 0; i < 2; i++) {
    float invl[4];
    for (int r = 0; r < 4; r++)
      invl[r] = 0.044194173824159216f / accl[i][r];  // 1/(l*sqrt(512))
    for (int n = 0; n < 4; n++) {
      int col = n0 + wc + n * 16 + c16;
      for (int r = 0; r < 4; r++) {
        int row = m0 + wr + i * 16 + q * 4 + r;
        C[(size_t)row * DDIM + col] = f2b(acc[i][n][r] * invl[r]);
      }
    }
  }
}

// XCD-grouping remap for pv blocks (bid in 0..511)
DEV void pv_remap(int bid, int& bx, int& by) {
  bx = (bid >> 3) & 3;
  by = (bid & 7) + 8 * (bid >> 5);
}

// XCD-chunked remap for scores sub-grid (sb in 0..2047, 64x32 tiles):
// each XCD owns a contiguous quarter of by-space -> Q-panels L2-resident.
DEV void scores_remap(int sb, int& bx, int& by) {
  int L = (sb & 7) * 256 + (sb >> 3);
  bx = L & 63;
  by = L >> 6;
}

// scores: P = exp(Q K^T - 48)   grid (2048)  (fallback path only)
__global__ __launch_bounds__(256, 2) void scores_kernel(
    const u16* __restrict__ Q, const u16* __restrict__ Kv,
    u16* __restrict__ P) {
  __shared__ u16 lds[24576];
  int bx, by;
  scores_remap(blockIdx.x, bx, by);
  gemm_core<1>(Q, Kv, P, nullptr, lds, DDIM, DDIM, DDIM, NR, bx, by);
}

// qproj (z-batched): Q_z = X_z W_z^T + b_z   grid (4,32,nz)
__global__ __launch_bounds__(256, 2) void qproj_kernel(
    const u16* __restrict__ s0, const u16* __restrict__ s1,
    const u16* __restrict__ s2, const u16* __restrict__ s3,
    const u16* __restrict__ Wb, const float* __restrict__ b0,
    const float* __restrict__ b1, const float* __restrict__ b2,
    const float* __restrict__ b3, u16* __restrict__ Qs) {
  __shared__ u16 lds[24576];
  int z = blockIdx.z;
  const u16* A = z == 0 ? s0 : (z == 1 ? s1 : (z == 2 ? s2 : s3));
  const float* bias = z == 0 ? b0 : (z == 1 ? b1 : (z == 2 ? b2 : b3));
  gemm_core<0>(A, Wb + (size_t)z * DDIM * DDIM, Qs + (size_t)z * NR * DDIM,
               bias, lds, DDIM, DDIM, DDIM, DDIM, blockIdx.x, blockIdx.y);
}

// qscombo: blocks 0..383 -> qproj z=1..3 (128 each); 384.. -> scores_0
__global__ __launch_bounds__(256, 2) void qscombo_kernel(
    const u16* __restrict__ x1b, const u16* __restrict__ x2b,
    const u16* __restrict__ x4b, const u16* __restrict__ Wb,
    const float* __restrict__ b1, const float* __restrict__ b2,
    const float* __restrict__ b3, u16* __restrict__ Qs,
    const u16* __restrict__ Q0, u16* __restrict__ P) {
  __shared__ u16 lds[24576];
  if (blockIdx.x < 384) {
    int b = blockIdx.x;
    int z = 1 + (b >> 7), rem = b & 127;
    const u16* A = z == 1 ? x2b : (z == 2 ? x1b : x4b);
    const float* bias = z == 1 ? b1 : (z == 2 ? b2 : b3);
    gemm_core<0>(A, Wb + (size_t)z * DDIM * DDIM, Qs + (size_t)z * NR * DDIM,
                 bias, lds, DDIM, DDIM, DDIM, DDIM, rem & 3, rem >> 2);
  } else {
    int sb = blockIdx.x - 384;  // 384 % 8 == 0 -> sb%8 preserves XCD id
    int bx, by;
    scores_remap(sb, bx, by);
    gemm_core<1>(Q0, x2b, P, nullptr, lds, DDIM, DDIM, DDIM, NR, bx, by);
  }
}

// standalone PV   grid (512)
__global__ __launch_bounds__(256, 3) void pv_kernel(
    const u16* __restrict__ A, const u16* __restrict__ B,
    u16* __restrict__ C) {
  __shared__ u16 lds[24576];
  int bx, by;
  pv_remap(blockIdx.x, bx, by);
  pv_body(A, B, lds, C, bx, by);
}

// combo: blocks 0..511 -> pv_a (Pin->F); blocks 512.. -> scores_{a+1}
__global__ __launch_bounds__(256, 2) void combo_kernel(
    const u16* __restrict__ Pin, const u16* __restrict__ Vt,
    u16* __restrict__ F, const u16* __restrict__ Q,
    const u16* __restrict__ Kv, u16* __restrict__ Pout) {
  __shared__ u16 lds[24576];
  if (blockIdx.x < 512) {
    int bx, by;
    pv_remap(blockIdx.x, bx, by);
    pv_body(Pin, Vt, lds, F, bx, by);
  } else {
    int sb = blockIdx.x - 512;  // 512 % 8 == 0
    int bx, by;
    scores_remap(sb, bx, by);
    gemm_core<1>(Q, Kv, Pout, nullptr, lds, DDIM, DDIM, DDIM, NR, bx, by);
  }
}

// ---------------- fused head: concat+relu+Wp+bias+gate ----------------
__global__ __launch_bounds__(256) void head_kernel(
    const u16* __restrict__ F1, const u16* __restrict__ F2,
    const u16* __restrict__ F3, const u16* __restrict__ F4,
    const u16* __restrict__ x1, const u16* __restrict__ x2,
    const u16* __restrict__ x4, const float* __restrict__ Wp,
    const float* __restrict__ bp, const float* __restrict__ tg,
    const float* __restrict__ Wt1, const float* __restrict__ bt1,
    const float* __restrict__ Wt2, const float* __restrict__ bt2,
    float* __restrict__ out) {
  __shared__ float wps[TOUT * 2 * DDIM];
  __shared__ float t2s;
  int tid = threadIdx.x;
  for (int i = tid; i < TOUT * 2 * DDIM; i += 256) wps[i] = Wp[i];
  if (tid == 0) {
    float s = bt2[0];
    for (int k = 0; k < 50; k++) s += Wt2[k] * (tg[0] * Wt1[k] + bt1[k]);
    t2s = 1.0f / (1.0f + __expf(-s));
  }
  __syncthreads();
  int g = tid >> 5, j = tid & 31;
  size_t m = (size_t)blockIdx.x * 8 + g;
  float a12[TOUT] = {}, a34[TOUT] = {};
  for (int d = j; d < 2 * DDIM; d += 32) {
    float h12, h34;
    if (d < DDIM) {
      float xv = b2f(x1[m * DDIM + d]);
      h12 = b2f(F1[m * DDIM + d]) + xv;
      h34 = b2f(F3[m * DDIM + d]) + xv;
    } else {
      int dd = d - DDIM;
      h12 = b2f(F2[m * DDIM + dd]) + b2f(x2[m * DDIM + dd]);
      h34 = b2f(F4[m * DDIM + dd]) + b2f(x4[m * DDIM + dd]);
    }
    h12 = fmaxf(h12, 0.f);
    h34 = fmaxf(h34, 0.f);
    for (int t = 0; t < TOUT; t++) {
      float wv = wps[t * 2 * DDIM + d];
      a12[t] += h12 * wv;
      a34[t] += h34 * wv;
    }
  }
  for (int off = 1; off < 32; off <<= 1)
    for (int t = 0; t < TOUT; t++) {
      a12[t] += __shfl_xor(a12[t], off);
      a34[t] += __shfl_xor(a34[t], off);
    }
  if (j < TOUT) {
    float t2 = t2s;
    out[m * TOUT + j] = t2 * a12[j] + (1.f - t2) * a34[j] + bp[j];
  }
}

extern "C" void kernel_launch(void* const* d_in, const int* in_sizes, int n_in,
                              void* d_out, int out_size, void* d_ws,
                              size_t ws_size, hipStream_t stream) {
  (void)in_sizes; (void)n_in; (void)out_size;
  const float* xp = (const float*)d_in[0];
  const float* xm = (const float*)d_in[1];
  const float* xs = (const float*)d_in[2];
  const float* ln_g = (const float*)d_in[3];
  const float* ln_b = (const float*)d_in[4];
  const float* Wmat[4] = {(const float*)d_in[5], (const float*)d_in[7],
                          (const float*)d_in[9], (const float*)d_in[11]};
  const float* bvec[4] = {(const float*)d_in[6], (const float*)d_in[8],
                          (const float*)d_in[10], (const float*)d_in[12]};
  const float* Wp = (const float*)d_in[13];
  const float* bp = (const float*)d_in[14];
  const float* tg = (const float*)d_in[15];
  const float* Wt1 = (const float*)d_in[16];
  const float* bt1 = (const float*)d_in[17];
  const float* Wt2 = (const float*)d_in[18];
  const float* bt2 = (const float*)d_in[19];
  float* out = (float*)d_out;

  char* ws = (char*)d_ws;
  const size_t MB = 1ull << 20;
  u16* x1b = (u16*)(ws + 0 * MB);
  u16* x2b = (u16*)(ws + 8 * MB);
  u16* x4b = (u16*)(ws + 16 * MB);
  u16* x1t = (u16*)(ws + 24 * MB);
  u16* x2t = (u16*)(ws + 32 * MB);
  u16* x4t = (u16*)(ws + 40 * MB);
  u16* Wb = (u16*)(ws + 48 * MB);
  u16* Qs = (u16*)(ws + 52 * MB);  // 4 slots of 8 MB; F_a overlays Q_a
  u16* P0 = (u16*)(ws + 84 * MB);  // 128 MiB
  bool dual = ws_size >= 340 * MB;
  u16* P1 = dual ? (u16*)(ws + 212 * MB) : P0;

  ln_kernel<<<dim3(NR, 3), 64, 0, stream>>>(xp, xm, xs, ln_g, ln_b, x1b, x2b,
                                            x4b);
  wconv_kernel<<<dim3(128, 4), 256, 0, stream>>>(Wmat[0], Wmat[1], Wmat[2],
                                                 Wmat[3], Wb);
  transpose_kernel<<<dim3(8, 128, 3), 256, 0, stream>>>(x1b, x2b, x4b, x1t,
                                                        x2t, x4t);
  // qproj z=0 only (scores_0 needs just slot 0)
  qproj_kernel<<<dim3(4, 32, 1), 256, 0, stream>>>(
      x1b, x2b, x1b, x4b, Wb, bvec[0], bvec[1], bvec[2], bvec[3], Qs);

  const u16* kvb[4] = {x2b, x1b, x4b, x1b};
  const u16* kvt[4] = {x2t, x1t, x4t, x1t};
  u16* slot[4];
  for (int a = 0; a < 4; a++) slot[a] = Qs + (size_t)a * NR * DDIM;

  // qproj z=1..3 packed with scores_0
  qscombo_kernel<<<dim3(384 + 2048), 256, 0, stream>>>(
      x1b, x2b, x4b, Wb, bvec[1], bvec[2], bvec[3], Qs, slot[0], P0);

  if (dual) {
    u16* Pb[4] = {P0, P1, P0, P1};
    for (int a = 0; a < 3; a++) {
      // pv_a (P_a -> F_a over Q_a) || scores_{a+1} (-> other P buffer)
      combo_kernel<<<dim3(512 + 2048), 256, 0, stream>>>(
          Pb[a], kvt[a], slot[a], slot[a + 1], kvb[a + 1], Pb[a + 1]);
    }
    pv_kernel<<<dim3(512), 256, 0, stream>>>(Pb[3], kvt[3], slot[3]);
  } else {
    for (int a = 0; a < 4; a++) {
      if (a > 0)
        scores_kernel<<<dim3(2048), 256, 0, stream>>>(slot[a], kvb[a], P0);
      pv_kernel<<<dim3(512), 256, 0, stream>>>(P0, kvt[a], slot[a]);
    }
  }

  // attention a -> f[fidx[a]]: a0->f2, a1->f1, a2->f4, a3->f3
  head_kernel<<<dim3(NR / 8), 256, 0, stream>>>(
      slot[1], slot[0], slot[3], slot[2], x1b, x2b, x4b, Wp, bp, tg, Wt1, bt1,
      Wt2, bt2, out);
}

// Round 7
// 888.604 us; speedup vs baseline: 1.1333x; 1.1333x over previous
//
#include <hip/hip_runtime.h>
#include <stdint.h>

// InteractionModel: N=8192, D=512, T=12. All inputs/outputs fp32.
// R12: R11's 256x128 tile REVERTED (occupancy 4->2 blocks/CU killed it:
//      MfmaUtil 33->24, FETCH 89->194MB). Back to R10's 128x128/BK=32, but
//      gemm_core K-loop is now 3-buffer SINGLE-barrier: stage(t+2) issued at
//      top of iter t into buf (t+2)%3 (last read at t-1); vmcnt(4)+barrier
//      retires tile t; no second barrier / lgkmcnt drain per K-step.
//      LDS 48KB -> 3 blocks/CU. pv_body unchanged from R10.
// Workspace: 0 x1b, 8 x2b, 16 x4b | 24/32/40 x1t/x2t/x4t | 48 Wb |
//   52 Qs (4x8MB, F_a overlays Q_a) | 84 P0 (128MB) | 212 P1 (128MB)

#define DEV __device__ __forceinline__
typedef unsigned short u16;
typedef __bf16 bf16x8 __attribute__((ext_vector_type(8)));
typedef float f32x4 __attribute__((ext_vector_type(4)));

constexpr int NR = 8192;
constexpr int DDIM = 512;
constexpr int TOUT = 12;

DEV u16 f2b(float f) {
  uint32_t u = __builtin_bit_cast(uint32_t, f);
  u += 0x7fffu + ((u >> 16) & 1u);
  return (u16)(u >> 16);
}
DEV float b2f(u16 h) {
  uint32_t u = ((uint32_t)h) << 16;
  return __builtin_bit_cast(float, u);
}

// ---------------- LayerNorm: fp32 in -> bf16 out ----------------
__global__ __launch_bounds__(64) void ln_kernel(
    const float* __restrict__ xp, const float* __restrict__ xm,
    const float* __restrict__ xs, const float* __restrict__ g,
    const float* __restrict__ b, u16* __restrict__ o1, u16* __restrict__ o2,
    u16* __restrict__ o4) {
  int row = blockIdx.x;
  int which = blockIdx.y;
  const float* x = which == 0 ? xp : (which == 1 ? xm : xs);
  u16* o = which == 0 ? o1 : (which == 1 ? o2 : o4);
  int lane = threadIdx.x;
  const float4* xr = (const float4*)(x + (size_t)row * DDIM);
  float4 v0 = xr[lane * 2], v1 = xr[lane * 2 + 1];
  float vals[8] = {v0.x, v0.y, v0.z, v0.w, v1.x, v1.y, v1.z, v1.w};
  float s = 0.f, s2 = 0.f;
  for (int j = 0; j < 8; j++) { s += vals[j]; s2 += vals[j] * vals[j]; }
  for (int off = 1; off < 64; off <<= 1) {
    s += __shfl_xor(s, off);
    s2 += __shfl_xor(s2, off);
  }
  float m = s * (1.0f / DDIM);
  float var = s2 * (1.0f / DDIM) - m * m;
  var = fmaxf(var, 0.f);
  float rs = rsqrtf(var + 1e-6f);
  int d0 = lane * 8;
  u16 us[8];
  for (int j = 0; j < 8; j++)
    us[j] = f2b((vals[j] - m) * rs * g[d0 + j] + b[d0 + j]);
  uint4 pk;
  pk.x = (uint32_t)us[0] | ((uint32_t)us[1] << 16);
  pk.y = (uint32_t)us[2] | ((uint32_t)us[3] << 16);
  pk.z = (uint32_t)us[4] | ((uint32_t)us[5] << 16);
  pk.w = (uint32_t)us[6] | ((uint32_t)us[7] << 16);
  *(uint4*)(o + (size_t)row * DDIM + d0) = pk;
}

// ---------------- W fp32 -> bf16 ----------------
__global__ __launch_bounds__(256) void wconv_kernel(
    const float* __restrict__ W1, const float* __restrict__ W2,
    const float* __restrict__ W3, const float* __restrict__ W4,
    u16* __restrict__ Wb) {
  int wi = blockIdx.y;
  const float* W = wi == 0 ? W1 : (wi == 1 ? W2 : (wi == 2 ? W3 : W4));
  size_t base = ((size_t)blockIdx.x * 256 + threadIdx.x) * 8;
  const float4* src = (const float4*)(W + base);
  float4 a = src[0], c = src[1];
  float vals[8] = {a.x, a.y, a.z, a.w, c.x, c.y, c.z, c.w};
  u16 us[8];
  for (int j = 0; j < 8; j++) us[j] = f2b(vals[j]);
  uint4 pk;
  pk.x = (uint32_t)us[0] | ((uint32_t)us[1] << 16);
  pk.y = (uint32_t)us[2] | ((uint32_t)us[3] << 16);
  pk.z = (uint32_t)us[4] | ((uint32_t)us[5] << 16);
  pk.w = (uint32_t)us[6] | ((uint32_t)us[7] << 16);
  *(uint4*)(Wb + (size_t)wi * DDIM * DDIM + base) = pk;
}

// ---------------- bf16 transpose [8192][512] -> [512][8192] ----------------
__global__ __launch_bounds__(256) void transpose_kernel(
    const u16* __restrict__ s1, const u16* __restrict__ s2,
    const u16* __restrict__ s4, u16* __restrict__ t1, u16* __restrict__ t2,
    u16* __restrict__ t4) {
  constexpr int LD = 66;
  __shared__ u16 tile[64 * LD];
  int which = blockIdx.z;
  const u16* src = which == 0 ? s1 : (which == 1 ? s2 : s4);
  u16* dst = which == 0 ? t1 : (which == 1 ? t2 : t4);
  int c0 = blockIdx.x * 64;
  int r0 = blockIdx.y * 64;
  int tid = threadIdx.x;
  for (int c = tid; c < 512; c += 256) {
    int i = c >> 3, j8 = (c & 7) * 8;
    uint4 v = *(const uint4*)(src + (size_t)(r0 + i) * DDIM + c0 + j8);
    uint32_t* dw = (uint32_t*)&tile[i * LD + j8];
    dw[0] = v.x; dw[1] = v.y; dw[2] = v.z; dw[3] = v.w;
  }
  __syncthreads();
  for (int rep = 0; rep < 2; rep++) {
    int idx = rep * 256 + tid;
    int o = idx >> 3, j8 = (idx & 7) * 8;
    u16 us[8];
    for (int k = 0; k < 8; k++) us[k] = tile[(j8 + k) * LD + o];
    uint4 pk;
    pk.x = (uint32_t)us[0] | ((uint32_t)us[1] << 16);
    pk.y = (uint32_t)us[2] | ((uint32_t)us[3] << 16);
    pk.z = (uint32_t)us[4] | ((uint32_t)us[5] << 16);
    pk.w = (uint32_t)us[6] | ((uint32_t)us[7] << 16);
    *(uint4*)(dst + (size_t)(c0 + o) * NR + r0 + j8) = pk;
  }
}

// ---------------- shared bt-GEMM core (BM=BN=128, BK=32, 2x2 wave grid) ----
// R12: 3-buffer single-barrier pipeline. Per iter t: vmcnt(4) [retire tile
// t's loads; keep t+1's in flight] -> barrier -> stage(t+2) into buf
// (t+2)%3 -> ds_read buf t%3 -> MFMA. Buf (t+2)%3 was last read at t-1 and
// its old loads retired by t-1's vmcnt -> safe. One barrier per K-step.
// LDS slot (row,s) holds global chunk (s-(row>>1))&3; reader uses
// s=(q+(r>>1))&3 -> bank-group (4r+s)%8 covers all 8 -> 2-way (free).
// MODE 0: out bf16 = acc + bias[col]   MODE 1: out bf16 = exp(acc - 48)
// lds: 24576 u16 (48 KB): buf b at b*8192 (A 4096 | B 4096).
template <int MODE>
DEV void gemm_core(const u16* __restrict__ A, const u16* __restrict__ B,
                   u16* __restrict__ C, const float* __restrict__ bias,
                   u16* lds, int K, int lda, int ldb, int ldc, int bx,
                   int by) {
  constexpr int TM = 4, TN = 4;
  int tid = threadIdx.x;
  int w = tid >> 6, lane = tid & 63;
  int q = lane >> 4, c16 = lane & 15;
  int n0 = bx * 128, m0 = by * 128;
  int wrow = (w >> 1) * 64, wcol = (w & 1) * 64;

  // hoisted staging pointers: this wave handles calls w, w+4, w+8, w+12
  const u16* gptr[4];
  int lof[4];  // u16 offset within a buffer (wave-uniform base)
#pragma unroll
  for (int j = 0; j < 4; j++) {
    int call = w + j * 4;
    bool isA = call < 8;
    int ci = isA ? call : call - 8;
    int chunk = ci * 64 + lane;
    int row = chunk >> 2;
    int gch = ((chunk & 3) - (row >> 1)) & 3;  // source chunk for this slot
    gptr[j] = isA ? (A + (size_t)(m0 + row) * lda + gch * 8)
                  : (B + (size_t)(n0 + row) * ldb + gch * 8);
    lof[j] = (isA ? 0 : 4096) + ci * 512;
  }
  auto stageAll = [&](int buf) {
    int bo = buf * 8192;
#pragma unroll
    for (int j = 0; j < 4; j++) {
      __builtin_amdgcn_global_load_lds(
          (const __attribute__((address_space(1))) void*)gptr[j],
          (__attribute__((address_space(3))) void*)(lds + bo + lof[j]), 16, 0,
          0);
      gptr[j] += 32;  // next K-step (32 u16 = 64 B)
    }
  };

  f32x4 acc[TM][TN] = {};
  int nk = K >> 5;  // 16 for K=512
  stageAll(0);   // tile 0 -> buf 0
  stageAll(1);   // tile 1 -> buf 1; 8 loads in flight per wave
  int cur = 0;   // = ks % 3
  for (int ks = 0; ks < nk; ks++) {
    if (ks + 1 < nk)
      asm volatile("s_waitcnt vmcnt(4)" ::: "memory");
    else
      asm volatile("s_waitcnt vmcnt(0)" ::: "memory");
    __builtin_amdgcn_sched_barrier(0);
    __builtin_amdgcn_s_barrier();
    __builtin_amdgcn_sched_barrier(0);
    if (ks + 2 < nk) {
      int nb = cur + 2;
      if (nb >= 3) nb -= 3;
      stageAll(nb);  // tile ks+2 -> buf (ks+2)%3 (last read at ks-1)
    }
    const u16* Asm = lds + cur * 8192;
    const u16* Bsm = Asm + 4096;
    bf16x8 af[TM], bfr[TN];
#pragma unroll
    for (int i = 0; i < TM; i++) {
      int r = wrow + i * 16 + c16;
      af[i] = *(const bf16x8*)&Asm[r * 32 + (((q + (r >> 1)) & 3) * 8)];
    }
#pragma unroll
    for (int n = 0; n < TN; n++) {
      int r = wcol + n * 16 + c16;
      bfr[n] = *(const bf16x8*)&Bsm[r * 32 + (((q + (r >> 1)) & 3) * 8)];
    }
    __builtin_amdgcn_s_setprio(1);
#pragma unroll
    for (int i = 0; i < TM; i++)
#pragma unroll
      for (int n = 0; n < TN; n++)
        acc[i][n] = __builtin_amdgcn_mfma_f32_16x16x32_bf16(af[i], bfr[n],
                                                            acc[i][n], 0, 0, 0);
    __builtin_amdgcn_s_setprio(0);
    cur++;
    if (cur >= 3) cur -= 3;
  }
  // ---- coalesced epilogue: two passes over col-halves of the 128x128 tile --
  for (int h = 0; h < 2; h++) {
    __syncthreads();
    if ((w & 1) == h) {
      for (int i = 0; i < TM; i++) {
        for (int n = 0; n < TN; n++) {
          float bv = 0.f;
          if constexpr (MODE == 0) bv = bias[n0 + wcol + n * 16 + c16];
          for (int r = 0; r < 4; r++) {
            int rl = wrow + i * 16 + q * 4 + r;                // 0..127
            int cl = (n * 16 + c16) ^ ((rl & 7) << 3);         // swizzled col
            float v = acc[i][n][r];
            if constexpr (MODE == 0) v += bv;
            if constexpr (MODE == 1) v = __expf(v - 48.0f);
            lds[rl * 64 + cl] = f2b(v);
          }
        }
      }
    }
    __syncthreads();
    for (int rep = 0; rep < 4; rep++) {
      int idx = rep * 256 + tid;  // 0..1023 uint4s = 128 rows x 8 segs
      int row = idx >> 3, seg = idx & 7;
      uint4 vv = ((const uint4*)lds)[row * 8 + (seg ^ (row & 7))];
      *(uint4*)(C + (size_t)(m0 + row) * ldc + n0 + h * 64 + seg * 8) = vv;
    }
  }
}

// ---------------- PV body: F = (P V)/(l sqrt512) ----------
// BM=64, BN=128, BK=64; 512 blocks. Counted-vmcnt 2-buffer pipeline (R10,
// proven). lds: 24576 u16 (48 KB): A dbuf [0,8192), B dbuf [8192,24576).
DEV void pv_body(const u16* __restrict__ A, const u16* __restrict__ B,
                 u16* lds, u16* __restrict__ C, int bx, int by) {
  constexpr int BM = 64, BN = 128, BK = 64;
  int tid = threadIdx.x, w = tid >> 6, lane = tid & 63;
  int q = lane >> 4, c16 = lane & 15;
  int n0 = bx * BN, m0 = by * BM;
  int wr = (w >> 1) * 32, wc = (w & 1) * 64;
  f32x4 acc[2][4] = {};
  f32x4 accl[2] = {};
  bf16x8 ones;
  for (int j = 0; j < 8; j++) ones[j] = (__bf16)1.0f;

  const u16* gptr[6];
  int lof0[6], lof1[6];
#pragma unroll
  for (int it = 0; it < 6; it++) {
    int cb = it * 256 + w * 64;  // wave-uniform
    int c = cb + lane;
    bool isA = cb < 512;  // uniform per wave
    int ci = isA ? c : c - 512;
    int row = ci >> 3;
    int koff = ((ci & 7) ^ (row & 7)) * 8;  // full 8-group swizzle
    gptr[it] = isA ? (A + (size_t)(m0 + row) * NR + koff)
                   : (B + (size_t)(n0 + row) * NR + koff);
    lof0[it] = isA ? (cb * 8) : (8192 + (cb - 512) * 8);
    lof1[it] = isA ? (4096 + cb * 8) : (16384 + (cb - 512) * 8);
  }
  auto stage = [&](int buf) {
#pragma unroll
    for (int it = 0; it < 6; it++) {
      int lo = buf ? lof1[it] : lof0[it];
      __builtin_amdgcn_global_load_lds(
          (const __attribute__((address_space(1))) void*)gptr[it],
          (__attribute__((address_space(3))) void*)(lds + lo), 16, 0, 0);
      gptr[it] += BK;  // next K-tile (64 u16 = 128 B)
    }
  };

  constexpr int KSTEPS = NR / BK;
  stage(0);
  stage(1);  // 12 loads in flight
  for (int ks = 0; ks < KSTEPS; ks++) {
    int cur = ks & 1;
    if (ks + 1 < KSTEPS)
      asm volatile("s_waitcnt vmcnt(6)" ::: "memory");
    else
      asm volatile("s_waitcnt vmcnt(0)" ::: "memory");
    __builtin_amdgcn_sched_barrier(0);
    __builtin_amdgcn_s_barrier();
    __builtin_amdgcn_sched_barrier(0);
    const u16* Asm = lds + cur * 4096;
    const u16* Bsm = lds + 8192 + cur * 8192;
#pragma unroll
    for (int kh = 0; kh < 2; kh++) {
      bf16x8 af[2], bfr[4];
      int cl = kh * 4 + q;
#pragma unroll
      for (int i = 0; i < 2; i++) {
        int r = wr + i * 16 + c16;
        af[i] = *(const bf16x8*)&Asm[r * BK + ((cl ^ (r & 7)) * 8)];
      }
#pragma unroll
      for (int n = 0; n < 4; n++) {
        int r = wc + n * 16 + c16;
        bfr[n] = *(const bf16x8*)&Bsm[r * BK + ((cl ^ (r & 7)) * 8)];
      }
      __builtin_amdgcn_s_setprio(1);
#pragma unroll
      for (int i = 0; i < 2; i++)
        accl[i] = __builtin_amdgcn_mfma_f32_16x16x32_bf16(af[i], ones, accl[i],
                                                          0, 0, 0);
#pragma unroll
      for (int i = 0; i < 2; i++)
#pragma unroll
        for (int n = 0; n < 4; n++)
          acc[i][n] = __builtin_amdgcn_mfma_f32_16x16x32_bf16(
              af[i], bfr[n], acc[i][n], 0, 0, 0);
      __builtin_amdgcn_s_setprio(0);
    }
    asm volatile("s_waitcnt lgkmcnt(0)" ::: "memory");
    __builtin_amdgcn_sched_barrier(0);
    __builtin_amdgcn_s_barrier();
    __builtin_amdgcn_sched_barrier(0);
    if (ks + 2 < KSTEPS) stage(cur);  // refill freed buffer
  }
  for (int i = 0; i < 2; i++) {
    float invl[4];
    for (int r = 0; r < 4; r++)
      invl[r] = 0.044194173824159216f / accl[i][r];  // 1/(l*sqrt(512))
    for (int n = 0; n < 4; n++) {
      int col = n0 + wc + n * 16 + c16;
      for (int r = 0; r < 4; r++) {
        int row = m0 + wr + i * 16 + q * 4 + r;
        C[(size_t)row * DDIM + col] = f2b(acc[i][n][r] * invl[r]);
      }
    }
  }
}

// XCD-grouping remap for pv blocks (bid in 0..511): the 4 blocks sharing a
// by (and its 1MB P-panel) get bids congruent mod 8 -> same XCD L2.
DEV void pv_remap(int bid, int& bx, int& by) {
  bx = (bid >> 3) & 3;
  by = (bid & 7) + 8 * (bid >> 5);
}

// scores: P = exp(Q K^T - 48)   grid (64,64)  (fallback path only)
__global__ __launch_bounds__(256, 3) void scores_kernel(
    const u16* __restrict__ Q, const u16* __restrict__ Kv,
    u16* __restrict__ P) {
  __shared__ u16 lds[24576];
  gemm_core<1>(Q, Kv, P, nullptr, lds, DDIM, DDIM, DDIM, NR, blockIdx.x,
               blockIdx.y);
}

// qproj (z-batched): Q_z = X_z W_z^T + b_z   grid (4,64,nz)
__global__ __launch_bounds__(256, 3) void qproj_kernel(
    const u16* __restrict__ s0, const u16* __restrict__ s1,
    const u16* __restrict__ s2, const u16* __restrict__ s3,
    const u16* __restrict__ Wb, const float* __restrict__ b0,
    const float* __restrict__ b1, const float* __restrict__ b2,
    const float* __restrict__ b3, u16* __restrict__ Qs) {
  __shared__ u16 lds[24576];
  int z = blockIdx.z;
  const u16* A = z == 0 ? s0 : (z == 1 ? s1 : (z == 2 ? s2 : s3));
  const float* bias = z == 0 ? b0 : (z == 1 ? b1 : (z == 2 ? b2 : b3));
  gemm_core<0>(A, Wb + (size_t)z * DDIM * DDIM, Qs + (size_t)z * NR * DDIM,
               bias, lds, DDIM, DDIM, DDIM, DDIM, blockIdx.x, blockIdx.y);
}

// qscombo: blocks 0..767 -> qproj z=1..3; blocks 768.. -> scores_0
__global__ __launch_bounds__(256, 3) void qscombo_kernel(
    const u16* __restrict__ x1b, const u16* __restrict__ x2b,
    const u16* __restrict__ x4b, const u16* __restrict__ Wb,
    const float* __restrict__ b1, const float* __restrict__ b2,
    const float* __restrict__ b3, u16* __restrict__ Qs,
    const u16* __restrict__ Q0, u16* __restrict__ P) {
  __shared__ u16 lds[24576];
  if (blockIdx.x < 768) {
    int b = blockIdx.x;
    int z = 1 + (b >> 8), rem = b & 255;
    const u16* A = z == 1 ? x2b : (z == 2 ? x1b : x4b);
    const float* bias = z == 1 ? b1 : (z == 2 ? b2 : b3);
    gemm_core<0>(A, Wb + (size_t)z * DDIM * DDIM, Qs + (size_t)z * NR * DDIM,
                 bias, lds, DDIM, DDIM, DDIM, DDIM, rem & 3, rem >> 2);
  } else {
    int b = blockIdx.x - 768;
    gemm_core<1>(Q0, x2b, P, nullptr, lds, DDIM, DDIM, DDIM, NR, b & 63,
                 b >> 6);
  }
}

// standalone PV   grid (512)
__global__ __launch_bounds__(256, 3) void pv_kernel(
    const u16* __restrict__ A, const u16* __restrict__ B,
    u16* __restrict__ C) {
  __shared__ u16 lds[24576];
  int bx, by;
  pv_remap(blockIdx.x, bx, by);
  pv_body(A, B, lds, C, bx, by);
}

// combo: blocks 0..511 -> pv_a (Pin->F); blocks 512.. -> scores_{a+1}
__global__ __launch_bounds__(256, 3) void combo_kernel(
    const u16* __restrict__ Pin, const u16* __restrict__ Vt,
    u16* __restrict__ F, const u16* __restrict__ Q,
    const u16* __restrict__ Kv, u16* __restrict__ Pout) {
  __shared__ u16 lds[24576];
  if (blockIdx.x < 512) {
    int bx, by;
    pv_remap(blockIdx.x, bx, by);
    pv_body(Pin, Vt, lds, F, bx, by);
  } else {
    int b = blockIdx.x - 512;
    gemm_core<1>(Q, Kv, Pout, nullptr, lds, DDIM, DDIM, DDIM, NR, b & 63,
                 b >> 6);
  }
}

// ---------------- fused head: concat+relu+Wp+bias+gate ----------------
__global__ __launch_bounds__(256) void head_kernel(
    const u16* __restrict__ F1, const u16* __restrict__ F2,
    const u16* __restrict__ F3, const u16* __restrict__ F4,
    const u16* __restrict__ x1, const u16* __restrict__ x2,
    const u16* __restrict__ x4, const float* __restrict__ Wp,
    const float* __restrict__ bp, const float* __restrict__ tg,
    const float* __restrict__ Wt1, const float* __restrict__ bt1,
    const float* __restrict__ Wt2, const float* __restrict__ bt2,
    float* __restrict__ out) {
  __shared__ float wps[TOUT * 2 * DDIM];
  __shared__ float t2s;
  int tid = threadIdx.x;
  for (int i = tid; i < TOUT * 2 * DDIM; i += 256) wps[i] = Wp[i];
  if (tid == 0) {
    float s = bt2[0];
    for (int k = 0; k < 50; k++) s += Wt2[k] * (tg[0] * Wt1[k] + bt1[k]);
    t2s = 1.0f / (1.0f + __expf(-s));
  }
  __syncthreads();
  int g = tid >> 5, j = tid & 31;
  size_t m = (size_t)blockIdx.x * 8 + g;
  float a12[TOUT] = {}, a34[TOUT] = {};
  for (int d = j; d < 2 * DDIM; d += 32) {
    float h12, h34;
    if (d < DDIM) {
      float xv = b2f(x1[m * DDIM + d]);
      h12 = b2f(F1[m * DDIM + d]) + xv;
      h34 = b2f(F3[m * DDIM + d]) + xv;
    } else {
      int dd = d - DDIM;
      h12 = b2f(F2[m * DDIM + dd]) + b2f(x2[m * DDIM + dd]);
      h34 = b2f(F4[m * DDIM + dd]) + b2f(x4[m * DDIM + dd]);
    }
    h12 = fmaxf(h12, 0.f);
    h34 = fmaxf(h34, 0.f);
    for (int t = 0; t < TOUT; t++) {
      float wv = wps[t * 2 * DDIM + d];
      a12[t] += h12 * wv;
      a34[t] += h34 * wv;
    }
  }
  for (int off = 1; off < 32; off <<= 1)
    for (int t = 0; t < TOUT; t++) {
      a12[t] += __shfl_xor(a12[t], off);
      a34[t] += __shfl_xor(a34[t], off);
    }
  if (j < TOUT) {
    float t2 = t2s;
    out[m * TOUT + j] = t2 * a12[j] + (1.f - t2) * a34[j] + bp[j];
  }
}

extern "C" void kernel_launch(void* const* d_in, const int* in_sizes, int n_in,
                              void* d_out, int out_size, void* d_ws,
                              size_t ws_size, hipStream_t stream) {
  (void)in_sizes; (void)n_in; (void)out_size;
  const float* xp = (const float*)d_in[0];
  const float* xm = (const float*)d_in[1];
  const float* xs = (const float*)d_in[2];
  const float* ln_g = (const float*)d_in[3];
  const float* ln_b = (const float*)d_in[4];
  const float* Wmat[4] = {(const float*)d_in[5], (const float*)d_in[7],
                          (const float*)d_in[9], (const float*)d_in[11]};
  const float* bvec[4] = {(const float*)d_in[6], (const float*)d_in[8],
                          (const float*)d_in[10], (const float*)d_in[12]};
  const float* Wp = (const float*)d_in[13];
  const float* bp = (const float*)d_in[14];
  const float* tg = (const float*)d_in[15];
  const float* Wt1 = (const float*)d_in[16];
  const float* bt1 = (const float*)d_in[17];
  const float* Wt2 = (const float*)d_in[18];
  const float* bt2 = (const float*)d_in[19];
  float* out = (float*)d_out;

  char* ws = (char*)d_ws;
  const size_t MB = 1ull << 20;
  u16* x1b = (u16*)(ws + 0 * MB);
  u16* x2b = (u16*)(ws + 8 * MB);
  u16* x4b = (u16*)(ws + 16 * MB);
  u16* x1t = (u16*)(ws + 24 * MB);
  u16* x2t = (u16*)(ws + 32 * MB);
  u16* x4t = (u16*)(ws + 40 * MB);
  u16* Wb = (u16*)(ws + 48 * MB);
  u16* Qs = (u16*)(ws + 52 * MB);  // 4 slots of 8 MB; F_a overlays Q_a
  u16* P0 = (u16*)(ws + 84 * MB);  // 128 MiB
  bool dual = ws_size >= 340 * MB;
  u16* P1 = dual ? (u16*)(ws + 212 * MB) : P0;

  ln_kernel<<<dim3(NR, 3), 64, 0, stream>>>(xp, xm, xs, ln_g, ln_b, x1b, x2b,
                                            x4b);
  wconv_kernel<<<dim3(128, 4), 256, 0, stream>>>(Wmat[0], Wmat[1], Wmat[2],
                                                 Wmat[3], Wb);
  transpose_kernel<<<dim3(8, 128, 3), 256, 0, stream>>>(x1b, x2b, x4b, x1t,
                                                        x2t, x4t);
  // qproj z=0 only (scores_0 needs just slot 0)
  qproj_kernel<<<dim3(DDIM / 128, NR / 128, 1), 256, 0, stream>>>(
      x1b, x2b, x1b, x4b, Wb, bvec[0], bvec[1], bvec[2], bvec[3], Qs);

  const u16* kvb[4] = {x2b, x1b, x4b, x1b};
  const u16* kvt[4] = {x2t, x1t, x4t, x1t};
  u16* slot[4];
  for (int a = 0; a < 4; a++) slot[a] = Qs + (size_t)a * NR * DDIM;

  // qproj z=1..3 packed with scores_0
  qscombo_kernel<<<dim3(768 + 64 * 64), 256, 0, stream>>>(
      x1b, x2b, x4b, Wb, bvec[1], bvec[2], bvec[3], Qs, slot[0], P0);

  if (dual) {
    u16* Pb[4] = {P0, P1, P0, P1};
    for (int a = 0; a < 3; a++) {
      // pv_a (P_a -> F_a over Q_a) || scores_{a+1} (-> other P buffer)
      combo_kernel<<<dim3(512 + 64 * 64), 256, 0, stream>>>(
          Pb[a], kvt[a], slot[a], slot[a + 1], kvb[a + 1], Pb[a + 1]);
    }
    pv_kernel<<<dim3(512), 256, 0, stream>>>(Pb[3], kvt[3], slot[3]);
  } else {
    for (int a = 0; a < 4; a++) {
      if (a > 0)
        scores_kernel<<<dim3(64, 64), 256, 0, stream>>>(slot[a], kvb[a], P0);
      pv_kernel<<<dim3(512), 256, 0, stream>>>(P0, kvt[a], slot[a]);
    }
  }

  // attention a -> f[fidx[a]]: a0->f2, a1->f1, a2->f4, a3->f3
  head_kernel<<<dim3(NR / 8), 256, 0, stream>>>(
      slot[1], slot[0], slot[3], slot[2], x1b, x2b, x4b, Wp, bp, tg, Wt1, bt1,
      Wt2, bt2, out);
}

// Round 8
// 886.725 us; speedup vs baseline: 1.1357x; 1.0021x over previous
//
#include <hip/hip_runtime.h>
#include <stdint.h>

// InteractionModel: N=8192, D=512, T=12. All inputs/outputs fp32.
// R13: R12 post-mortem: 3-buffer/1-barrier gemm REGRESSED qscombo (LDS 32->
//      48KB cost 4->3 blocks/CU; 110->140us) but IMPROVED combos (already at
//      48KB for pv_body -> barrier removal was free). So: template both —
//      TRIPLE=false (2-buf/2-barrier, 32KB, 4 blocks/CU) for qscombo/scores/
//      qproj; TRIPLE=true (3-buf/1-barrier) inside combo only.
// Workspace: 0 x1b, 8 x2b, 16 x4b | 24/32/40 x1t/x2t/x4t | 48 Wb |
//   52 Qs (4x8MB, F_a overlays Q_a) | 84 P0 (128MB) | 212 P1 (128MB)

#define DEV __device__ __forceinline__
typedef unsigned short u16;
typedef __bf16 bf16x8 __attribute__((ext_vector_type(8)));
typedef float f32x4 __attribute__((ext_vector_type(4)));

constexpr int NR = 8192;
constexpr int DDIM = 512;
constexpr int TOUT = 12;

DEV u16 f2b(float f) {
  uint32_t u = __builtin_bit_cast(uint32_t, f);
  u += 0x7fffu + ((u >> 16) & 1u);
  return (u16)(u >> 16);
}
DEV float b2f(u16 h) {
  uint32_t u = ((uint32_t)h) << 16;
  return __builtin_bit_cast(float, u);
}

// ---------------- LayerNorm: fp32 in -> bf16 out ----------------
__global__ __launch_bounds__(64) void ln_kernel(
    const float* __restrict__ xp, const float* __restrict__ xm,
    const float* __restrict__ xs, const float* __restrict__ g,
    const float* __restrict__ b, u16* __restrict__ o1, u16* __restrict__ o2,
    u16* __restrict__ o4) {
  int row = blockIdx.x;
  int which = blockIdx.y;
  const float* x = which == 0 ? xp : (which == 1 ? xm : xs);
  u16* o = which == 0 ? o1 : (which == 1 ? o2 : o4);
  int lane = threadIdx.x;
  const float4* xr = (const float4*)(x + (size_t)row * DDIM);
  float4 v0 = xr[lane * 2], v1 = xr[lane * 2 + 1];
  float vals[8] = {v0.x, v0.y, v0.z, v0.w, v1.x, v1.y, v1.z, v1.w};
  float s = 0.f, s2 = 0.f;
  for (int j = 0; j < 8; j++) { s += vals[j]; s2 += vals[j] * vals[j]; }
  for (int off = 1; off < 64; off <<= 1) {
    s += __shfl_xor(s, off);
    s2 += __shfl_xor(s2, off);
  }
  float m = s * (1.0f / DDIM);
  float var = s2 * (1.0f / DDIM) - m * m;
  var = fmaxf(var, 0.f);
  float rs = rsqrtf(var + 1e-6f);
  int d0 = lane * 8;
  u16 us[8];
  for (int j = 0; j < 8; j++)
    us[j] = f2b((vals[j] - m) * rs * g[d0 + j] + b[d0 + j]);
  uint4 pk;
  pk.x = (uint32_t)us[0] | ((uint32_t)us[1] << 16);
  pk.y = (uint32_t)us[2] | ((uint32_t)us[3] << 16);
  pk.z = (uint32_t)us[4] | ((uint32_t)us[5] << 16);
  pk.w = (uint32_t)us[6] | ((uint32_t)us[7] << 16);
  *(uint4*)(o + (size_t)row * DDIM + d0) = pk;
}

// ---------------- W fp32 -> bf16 ----------------
__global__ __launch_bounds__(256) void wconv_kernel(
    const float* __restrict__ W1, const float* __restrict__ W2,
    const float* __restrict__ W3, const float* __restrict__ W4,
    u16* __restrict__ Wb) {
  int wi = blockIdx.y;
  const float* W = wi == 0 ? W1 : (wi == 1 ? W2 : (wi == 2 ? W3 : W4));
  size_t base = ((size_t)blockIdx.x * 256 + threadIdx.x) * 8;
  const float4* src = (const float4*)(W + base);
  float4 a = src[0], c = src[1];
  float vals[8] = {a.x, a.y, a.z, a.w, c.x, c.y, c.z, c.w};
  u16 us[8];
  for (int j = 0; j < 8; j++) us[j] = f2b(vals[j]);
  uint4 pk;
  pk.x = (uint32_t)us[0] | ((uint32_t)us[1] << 16);
  pk.y = (uint32_t)us[2] | ((uint32_t)us[3] << 16);
  pk.z = (uint32_t)us[4] | ((uint32_t)us[5] << 16);
  pk.w = (uint32_t)us[6] | ((uint32_t)us[7] << 16);
  *(uint4*)(Wb + (size_t)wi * DDIM * DDIM + base) = pk;
}

// ---------------- bf16 transpose [8192][512] -> [512][8192] ----------------
__global__ __launch_bounds__(256) void transpose_kernel(
    const u16* __restrict__ s1, const u16* __restrict__ s2,
    const u16* __restrict__ s4, u16* __restrict__ t1, u16* __restrict__ t2,
    u16* __restrict__ t4) {
  constexpr int LD = 66;
  __shared__ u16 tile[64 * LD];
  int which = blockIdx.z;
  const u16* src = which == 0 ? s1 : (which == 1 ? s2 : s4);
  u16* dst = which == 0 ? t1 : (which == 1 ? t2 : t4);
  int c0 = blockIdx.x * 64;
  int r0 = blockIdx.y * 64;
  int tid = threadIdx.x;
  for (int c = tid; c < 512; c += 256) {
    int i = c >> 3, j8 = (c & 7) * 8;
    uint4 v = *(const uint4*)(src + (size_t)(r0 + i) * DDIM + c0 + j8);
    uint32_t* dw = (uint32_t*)&tile[i * LD + j8];
    dw[0] = v.x; dw[1] = v.y; dw[2] = v.z; dw[3] = v.w;
  }
  __syncthreads();
  for (int rep = 0; rep < 2; rep++) {
    int idx = rep * 256 + tid;
    int o = idx >> 3, j8 = (idx & 7) * 8;
    u16 us[8];
    for (int k = 0; k < 8; k++) us[k] = tile[(j8 + k) * LD + o];
    uint4 pk;
    pk.x = (uint32_t)us[0] | ((uint32_t)us[1] << 16);
    pk.y = (uint32_t)us[2] | ((uint32_t)us[3] << 16);
    pk.z = (uint32_t)us[4] | ((uint32_t)us[5] << 16);
    pk.w = (uint32_t)us[6] | ((uint32_t)us[7] << 16);
    *(uint4*)(dst + (size_t)(c0 + o) * NR + r0 + j8) = pk;
  }
}

// ---------------- shared bt-GEMM core (BM=BN=128, BK=32, 2x2 wave grid) ----
// TRIPLE=false: 2-buffer 2-barrier (R10), lds >= 16384 u16 (32 KB).
// TRIPLE=true:  3-buffer 1-barrier (R12), lds >= 24576 u16 (48 KB).
// LDS slot (row,s) holds global chunk (s-(row>>1))&3; reader uses
// s=(q+(r>>1))&3 -> bank-group (4r+s)%8 covers all 8 -> 2-way (free).
// MODE 0: out bf16 = acc + bias[col]   MODE 1: out bf16 = exp(acc - 48)
template <int MODE, bool TRIPLE>
DEV void gemm_core(const u16* __restrict__ A, const u16* __restrict__ B,
                   u16* __restrict__ C, const float* __restrict__ bias,
                   u16* lds, int K, int lda, int ldb, int ldc, int bx,
                   int by) {
  constexpr int TM = 4, TN = 4;
  int tid = threadIdx.x;
  int w = tid >> 6, lane = tid & 63;
  int q = lane >> 4, c16 = lane & 15;
  int n0 = bx * 128, m0 = by * 128;
  int wrow = (w >> 1) * 64, wcol = (w & 1) * 64;

  // hoisted staging pointers: this wave handles calls w, w+4, w+8, w+12
  const u16* gptr[4];
  int lof[4];  // u16 offset within a buffer (wave-uniform base)
#pragma unroll
  for (int j = 0; j < 4; j++) {
    int call = w + j * 4;
    bool isA = call < 8;
    int ci = isA ? call : call - 8;
    int chunk = ci * 64 + lane;
    int row = chunk >> 2;
    int gch = ((chunk & 3) - (row >> 1)) & 3;  // source chunk for this slot
    gptr[j] = isA ? (A + (size_t)(m0 + row) * lda + gch * 8)
                  : (B + (size_t)(n0 + row) * ldb + gch * 8);
    lof[j] = (isA ? 0 : 4096) + ci * 512;
  }
  auto stageAll = [&](int buf) {
    int bo = buf * 8192;
#pragma unroll
    for (int j = 0; j < 4; j++) {
      __builtin_amdgcn_global_load_lds(
          (const __attribute__((address_space(1))) void*)gptr[j],
          (__attribute__((address_space(3))) void*)(lds + bo + lof[j]), 16, 0,
          0);
      gptr[j] += 32;  // next K-step (32 u16 = 64 B)
    }
  };

  f32x4 acc[TM][TN] = {};
  int nk = K >> 5;  // 16 for K=512
  stageAll(0);
  stageAll(1);  // 8 loads in flight per wave
  int cur = 0;
  for (int ks = 0; ks < nk; ks++) {
    if (ks + 1 < nk)
      asm volatile("s_waitcnt vmcnt(4)" ::: "memory");
    else
      asm volatile("s_waitcnt vmcnt(0)" ::: "memory");
    __builtin_amdgcn_sched_barrier(0);
    __builtin_amdgcn_s_barrier();
    __builtin_amdgcn_sched_barrier(0);
    if constexpr (TRIPLE) {
      if (ks + 2 < nk) {
        int nb = cur + 2;
        if (nb >= 3) nb -= 3;
        stageAll(nb);  // tile ks+2 -> buf (ks+2)%3 (last read at ks-1)
      }
    }
    const u16* Asm = lds + cur * 8192;
    const u16* Bsm = Asm + 4096;
    bf16x8 af[TM], bfr[TN];
#pragma unroll
    for (int i = 0; i < TM; i++) {
      int r = wrow + i * 16 + c16;
      af[i] = *(const bf16x8*)&Asm[r * 32 + (((q + (r >> 1)) & 3) * 8)];
    }
#pragma unroll
    for (int n = 0; n < TN; n++) {
      int r = wcol + n * 16 + c16;
      bfr[n] = *(const bf16x8*)&Bsm[r * 32 + (((q + (r >> 1)) & 3) * 8)];
    }
    __builtin_amdgcn_s_setprio(1);
#pragma unroll
    for (int i = 0; i < TM; i++)
#pragma unroll
      for (int n = 0; n < TN; n++)
        acc[i][n] = __builtin_amdgcn_mfma_f32_16x16x32_bf16(af[i], bfr[n],
                                                            acc[i][n], 0, 0, 0);
    __builtin_amdgcn_s_setprio(0);
    if constexpr (!TRIPLE) {
      asm volatile("s_waitcnt lgkmcnt(0)" ::: "memory");
      __builtin_amdgcn_sched_barrier(0);
      __builtin_amdgcn_s_barrier();
      __builtin_amdgcn_sched_barrier(0);
      if (ks + 2 < nk) stageAll(cur);  // refill the buffer just consumed
      cur ^= 1;
    } else {
      cur++;
      if (cur >= 3) cur -= 3;
    }
  }
  // ---- coalesced epilogue: two passes over col-halves of the 128x128 tile --
  for (int h = 0; h < 2; h++) {
    __syncthreads();
    if ((w & 1) == h) {
      for (int i = 0; i < TM; i++) {
        for (int n = 0; n < TN; n++) {
          float bv = 0.f;
          if constexpr (MODE == 0) bv = bias[n0 + wcol + n * 16 + c16];
          for (int r = 0; r < 4; r++) {
            int rl = wrow + i * 16 + q * 4 + r;                // 0..127
            int cl = (n * 16 + c16) ^ ((rl & 7) << 3);         // swizzled col
            float v = acc[i][n][r];
            if constexpr (MODE == 0) v += bv;
            if constexpr (MODE == 1) v = __expf(v - 48.0f);
            lds[rl * 64 + cl] = f2b(v);
          }
        }
      }
    }
    __syncthreads();
    for (int rep = 0; rep < 4; rep++) {
      int idx = rep * 256 + tid;  // 0..1023 uint4s = 128 rows x 8 segs
      int row = idx >> 3, seg = idx & 7;
      uint4 vv = ((const uint4*)lds)[row * 8 + (seg ^ (row & 7))];
      *(uint4*)(C + (size_t)(m0 + row) * ldc + n0 + h * 64 + seg * 8) = vv;
    }
  }
}

// ---------------- PV body: F = (P V)/(l sqrt512) ----------
// BM=64, BN=128, BK=64; 512 blocks. Counted-vmcnt 2-buffer pipeline (R10,
// proven). lds: 24576 u16 (48 KB): A dbuf [0,8192), B dbuf [8192,24576).
DEV void pv_body(const u16* __restrict__ A, const u16* __restrict__ B,
                 u16* lds, u16* __restrict__ C, int bx, int by) {
  constexpr int BM = 64, BN = 128, BK = 64;
  int tid = threadIdx.x, w = tid >> 6, lane = tid & 63;
  int q = lane >> 4, c16 = lane & 15;
  int n0 = bx * BN, m0 = by * BM;
  int wr = (w >> 1) * 32, wc = (w & 1) * 64;
  f32x4 acc[2][4] = {};
  f32x4 accl[2] = {};
  bf16x8 ones;
  for (int j = 0; j < 8; j++) ones[j] = (__bf16)1.0f;

  const u16* gptr[6];
  int lof0[6], lof1[6];
#pragma unroll
  for (int it = 0; it < 6; it++) {
    int cb = it * 256 + w * 64;  // wave-uniform
    int c = cb + lane;
    bool isA = cb < 512;  // uniform per wave
    int ci = isA ? c : c - 512;
    int row = ci >> 3;
    int koff = ((ci & 7) ^ (row & 7)) * 8;  // full 8-group swizzle
    gptr[it] = isA ? (A + (size_t)(m0 + row) * NR + koff)
                   : (B + (size_t)(n0 + row) * NR + koff);
    lof0[it] = isA ? (cb * 8) : (8192 + (cb - 512) * 8);
    lof1[it] = isA ? (4096 + cb * 8) : (16384 + (cb - 512) * 8);
  }
  auto stage = [&](int buf) {
#pragma unroll
    for (int it = 0; it < 6; it++) {
      int lo = buf ? lof1[it] : lof0[it];
      __builtin_amdgcn_global_load_lds(
          (const __attribute__((address_space(1))) void*)gptr[it],
          (__attribute__((address_space(3))) void*)(lds + lo), 16, 0, 0);
      gptr[it] += BK;  // next K-tile (64 u16 = 128 B)
    }
  };

  constexpr int KSTEPS = NR / BK;
  stage(0);
  stage(1);  // 12 loads in flight
  for (int ks = 0; ks < KSTEPS; ks++) {
    int cur = ks & 1;
    if (ks + 1 < KSTEPS)
      asm volatile("s_waitcnt vmcnt(6)" ::: "memory");
    else
      asm volatile("s_waitcnt vmcnt(0)" ::: "memory");
    __builtin_amdgcn_sched_barrier(0);
    __builtin_amdgcn_s_barrier();
    __builtin_amdgcn_sched_barrier(0);
    const u16* Asm = lds + cur * 4096;
    const u16* Bsm = lds + 8192 + cur * 8192;
#pragma unroll
    for (int kh = 0; kh < 2; kh++) {
      bf16x8 af[2], bfr[4];
      int cl = kh * 4 + q;
#pragma unroll
      for (int i = 0; i < 2; i++) {
        int r = wr + i * 16 + c16;
        af[i] = *(const bf16x8*)&Asm[r * BK + ((cl ^ (r & 7)) * 8)];
      }
#pragma unroll
      for (int n = 0; n < 4; n++) {
        int r = wc + n * 16 + c16;
        bfr[n] = *(const bf16x8*)&Bsm[r * BK + ((cl ^ (r & 7)) * 8)];
      }
      __builtin_amdgcn_s_setprio(1);
#pragma unroll
      for (int i = 0; i < 2; i++)
        accl[i] = __builtin_amdgcn_mfma_f32_16x16x32_bf16(af[i], ones, accl[i],
                                                          0, 0, 0);
#pragma unroll
      for (int i = 0; i < 2; i++)
#pragma unroll
        for (int n = 0; n < 4; n++)
          acc[i][n] = __builtin_amdgcn_mfma_f32_16x16x32_bf16(
              af[i], bfr[n], acc[i][n], 0, 0, 0);
      __builtin_amdgcn_s_setprio(0);
    }
    asm volatile("s_waitcnt lgkmcnt(0)" ::: "memory");
    __builtin_amdgcn_sched_barrier(0);
    __builtin_amdgcn_s_barrier();
    __builtin_amdgcn_sched_barrier(0);
    if (ks + 2 < KSTEPS) stage(cur);  // refill freed buffer
  }
  for (int i = 0; i < 2; i++) {
    float invl[4];
    for (int r = 0; r < 4; r++)
      invl[r] = 0.044194173824159216f / accl[i][r];  // 1/(l*sqrt(512))
    for (int n = 0; n < 4; n++) {
      int col = n0 + wc + n * 16 + c16;
      for (int r = 0; r < 4; r++) {
        int row = m0 + wr + i * 16 + q * 4 + r;
        C[(size_t)row * DDIM + col] = f2b(acc[i][n][r] * invl[r]);
      }
    }
  }
}

// XCD-grouping remap for pv blocks (bid in 0..511): the 4 blocks sharing a
// by (and its 1MB P-panel) get bids congruent mod 8 -> same XCD L2.
DEV void pv_remap(int bid, int& bx, int& by) {
  bx = (bid >> 3) & 3;
  by = (bid & 7) + 8 * (bid >> 5);
}

// scores: P = exp(Q K^T - 48)   grid (64,64)  (fallback path only)
__global__ __launch_bounds__(256, 4) void scores_kernel(
    const u16* __restrict__ Q, const u16* __restrict__ Kv,
    u16* __restrict__ P) {
  __shared__ u16 lds[16384];
  gemm_core<1, false>(Q, Kv, P, nullptr, lds, DDIM, DDIM, DDIM, NR,
                      blockIdx.x, blockIdx.y);
}

// qproj (z-batched): Q_z = X_z W_z^T + b_z   grid (4,64,nz)
__global__ __launch_bounds__(256, 4) void qproj_kernel(
    const u16* __restrict__ s0, const u16* __restrict__ s1,
    const u16* __restrict__ s2, const u16* __restrict__ s3,
    const u16* __restrict__ Wb, const float* __restrict__ b0,
    const float* __restrict__ b1, const float* __restrict__ b2,
    const float* __restrict__ b3, u16* __restrict__ Qs) {
  __shared__ u16 lds[16384];
  int z = blockIdx.z;
  const u16* A = z == 0 ? s0 : (z == 1 ? s1 : (z == 2 ? s2 : s3));
  const float* bias = z == 0 ? b0 : (z == 1 ? b1 : (z == 2 ? b2 : b3));
  gemm_core<0, false>(A, Wb + (size_t)z * DDIM * DDIM,
                      Qs + (size_t)z * NR * DDIM, bias, lds, DDIM, DDIM, DDIM,
                      DDIM, blockIdx.x, blockIdx.y);
}

// qscombo: blocks 0..767 -> qproj z=1..3; blocks 768.. -> scores_0
__global__ __launch_bounds__(256, 4) void qscombo_kernel(
    const u16* __restrict__ x1b, const u16* __restrict__ x2b,
    const u16* __restrict__ x4b, const u16* __restrict__ Wb,
    const float* __restrict__ b1, const float* __restrict__ b2,
    const float* __restrict__ b3, u16* __restrict__ Qs,
    const u16* __restrict__ Q0, u16* __restrict__ P) {
  __shared__ u16 lds[16384];
  if (blockIdx.x < 768) {
    int b = blockIdx.x;
    int z = 1 + (b >> 8), rem = b & 255;
    const u16* A = z == 1 ? x2b : (z == 2 ? x1b : x4b);
    const float* bias = z == 1 ? b1 : (z == 2 ? b2 : b3);
    gemm_core<0, false>(A, Wb + (size_t)z * DDIM * DDIM,
                        Qs + (size_t)z * NR * DDIM, bias, lds, DDIM, DDIM,
                        DDIM, DDIM, rem & 3, rem >> 2);
  } else {
    int b = blockIdx.x - 768;
    gemm_core<1, false>(Q0, x2b, P, nullptr, lds, DDIM, DDIM, DDIM, NR,
                        b & 63, b >> 6);
  }
}

// standalone PV   grid (512)
__global__ __launch_bounds__(256, 3) void pv_kernel(
    const u16* __restrict__ A, const u16* __restrict__ B,
    u16* __restrict__ C) {
  __shared__ u16 lds[24576];
  int bx, by;
  pv_remap(blockIdx.x, bx, by);
  pv_body(A, B, lds, C, bx, by);
}

// combo: blocks 0..511 -> pv_a (Pin->F); blocks 512.. -> scores_{a+1}
__global__ __launch_bounds__(256, 3) void combo_kernel(
    const u16* __restrict__ Pin, const u16* __restrict__ Vt,
    u16* __restrict__ F, const u16* __restrict__ Q,
    const u16* __restrict__ Kv, u16* __restrict__ Pout) {
  __shared__ u16 lds[24576];
  if (blockIdx.x < 512) {
    int bx, by;
    pv_remap(blockIdx.x, bx, by);
    pv_body(Pin, Vt, lds, F, bx, by);
  } else {
    int b = blockIdx.x - 512;
    gemm_core<1, true>(Q, Kv, Pout, nullptr, lds, DDIM, DDIM, DDIM, NR,
                       b & 63, b >> 6);
  }
}

// ---------------- fused head: concat+relu+Wp+bias+gate ----------------
__global__ __launch_bounds__(256) void head_kernel(
    const u16* __restrict__ F1, const u16* __restrict__ F2,
    const u16* __restrict__ F3, const u16* __restrict__ F4,
    const u16* __restrict__ x1, const u16* __restrict__ x2,
    const u16* __restrict__ x4, const float* __restrict__ Wp,
    const float* __restrict__ bp, const float* __restrict__ tg,
    const float* __restrict__ Wt1, const float* __restrict__ bt1,
    const float* __restrict__ Wt2, const float* __restrict__ bt2,
    float* __restrict__ out) {
  __shared__ float wps[TOUT * 2 * DDIM];
  __shared__ float t2s;
  int tid = threadIdx.x;
  for (int i = tid; i < TOUT * 2 * DDIM; i += 256) wps[i] = Wp[i];
  if (tid == 0) {
    float s = bt2[0];
    for (int k = 0; k < 50; k++) s += Wt2[k] * (tg[0] * Wt1[k] + bt1[k]);
    t2s = 1.0f / (1.0f + __expf(-s));
  }
  __syncthreads();
  int g = tid >> 5, j = tid & 31;
  size_t m = (size_t)blockIdx.x * 8 + g;
  float a12[TOUT] = {}, a34[TOUT] = {};
  for (int d = j; d < 2 * DDIM; d += 32) {
    float h12, h34;
    if (d < DDIM) {
      float xv = b2f(x1[m * DDIM + d]);
      h12 = b2f(F1[m * DDIM + d]) + xv;
      h34 = b2f(F3[m * DDIM + d]) + xv;
    } else {
      int dd = d - DDIM;
      h12 = b2f(F2[m * DDIM + dd]) + b2f(x2[m * DDIM + dd]);
      h34 = b2f(F4[m * DDIM + dd]) + b2f(x4[m * DDIM + dd]);
    }
    h12 = fmaxf(h12, 0.f);
    h34 = fmaxf(h34, 0.f);
    for (int t = 0; t < TOUT; t++) {
      float wv = wps[t * 2 * DDIM + d];
      a12[t] += h12 * wv;
      a34[t] += h34 * wv;
    }
  }
  for (int off = 1; off < 32; off <<= 1)
    for (int t = 0; t < TOUT; t++) {
      a12[t] += __shfl_xor(a12[t], off);
      a34[t] += __shfl_xor(a34[t], off);
    }
  if (j < TOUT) {
    float t2 = t2s;
    out[m * TOUT + j] = t2 * a12[j] + (1.f - t2) * a34[j] + bp[j];
  }
}

extern "C" void kernel_launch(void* const* d_in, const int* in_sizes, int n_in,
                              void* d_out, int out_size, void* d_ws,
                              size_t ws_size, hipStream_t stream) {
  (void)in_sizes; (void)n_in; (void)out_size;
  const float* xp = (const float*)d_in[0];
  const float* xm = (const float*)d_in[1];
  const float* xs = (const float*)d_in[2];
  const float* ln_g = (const float*)d_in[3];
  const float* ln_b = (const float*)d_in[4];
  const float* Wmat[4] = {(const float*)d_in[5], (const float*)d_in[7],
                          (const float*)d_in[9], (const float*)d_in[11]};
  const float* bvec[4] = {(const float*)d_in[6], (const float*)d_in[8],
                          (const float*)d_in[10], (const float*)d_in[12]};
  const float* Wp = (const float*)d_in[13];
  const float* bp = (const float*)d_in[14];
  const float* tg = (const float*)d_in[15];
  const float* Wt1 = (const float*)d_in[16];
  const float* bt1 = (const float*)d_in[17];
  const float* Wt2 = (const float*)d_in[18];
  const float* bt2 = (const float*)d_in[19];
  float* out = (float*)d_out;

  char* ws = (char*)d_ws;
  const size_t MB = 1ull << 20;
  u16* x1b = (u16*)(ws + 0 * MB);
  u16* x2b = (u16*)(ws + 8 * MB);
  u16* x4b = (u16*)(ws + 16 * MB);
  u16* x1t = (u16*)(ws + 24 * MB);
  u16* x2t = (u16*)(ws + 32 * MB);
  u16* x4t = (u16*)(ws + 40 * MB);
  u16* Wb = (u16*)(ws + 48 * MB);
  u16* Qs = (u16*)(ws + 52 * MB);  // 4 slots of 8 MB; F_a overlays Q_a
  u16* P0 = (u16*)(ws + 84 * MB);  // 128 MiB
  bool dual = ws_size >= 340 * MB;
  u16* P1 = dual ? (u16*)(ws + 212 * MB) : P0;

  ln_kernel<<<dim3(NR, 3), 64, 0, stream>>>(xp, xm, xs, ln_g, ln_b, x1b, x2b,
                                            x4b);
  wconv_kernel<<<dim3(128, 4), 256, 0, stream>>>(Wmat[0], Wmat[1], Wmat[2],
                                                 Wmat[3], Wb);
  transpose_kernel<<<dim3(8, 128, 3), 256, 0, stream>>>(x1b, x2b, x4b, x1t,
                                                        x2t, x4t);
  // qproj z=0 only (scores_0 needs just slot 0)
  qproj_kernel<<<dim3(DDIM / 128, NR / 128, 1), 256, 0, stream>>>(
      x1b, x2b, x1b, x4b, Wb, bvec[0], bvec[1], bvec[2], bvec[3], Qs);

  const u16* kvb[4] = {x2b, x1b, x4b, x1b};
  const u16* kvt[4] = {x2t, x1t, x4t, x1t};
  u16* slot[4];
  for (int a = 0; a < 4; a++) slot[a] = Qs + (size_t)a * NR * DDIM;

  // qproj z=1..3 packed with scores_0
  qscombo_kernel<<<dim3(768 + 64 * 64), 256, 0, stream>>>(
      x1b, x2b, x4b, Wb, bvec[1], bvec[2], bvec[3], Qs, slot[0], P0);

  if (dual) {
    u16* Pb[4] = {P0, P1, P0, P1};
    for (int a = 0; a < 3; a++) {
      // pv_a (P_a -> F_a over Q_a) || scores_{a+1} (-> other P buffer)
      combo_kernel<<<dim3(512 + 64 * 64), 256, 0, stream>>>(
          Pb[a], kvt[a], slot[a], slot[a + 1], kvb[a + 1], Pb[a + 1]);
    }
    pv_kernel<<<dim3(512), 256, 0, stream>>>(Pb[3], kvt[3], slot[3]);
  } else {
    for (int a = 0; a < 4; a++) {
      if (a > 0)
        scores_kernel<<<dim3(64, 64), 256, 0, stream>>>(slot[a], kvb[a], P0);
      pv_kernel<<<dim3(512), 256, 0, stream>>>(P0, kvt[a], slot[a]);
    }
  }

  // attention a -> f[fidx[a]]: a0->f2, a1->f1, a2->f4, a3->f3
  head_kernel<<<dim3(NR / 8), 256, 0, stream>>>(
      slot[1], slot[0], slot[3], slot[2], x1b, x2b, x4b, Wp, bp, tg, Wt1, bt1,
      Wt2, bt2, out);
}

// Round 9
// 862.019 us; speedup vs baseline: 1.1683x; 1.0287x over previous
//
#include <hip/hip_runtime.h>
#include <stdint.h>

// InteractionModel: N=8192, D=512, T=12. All inputs/outputs fp32.
// R14: launch-chain compression. Known dispatch durs summed ~650us vs 886
//      total -> ~200us of serial small-dispatch + bubble time. (1) prep =
//      ln+wconv fused; (2) tqp = transpose + qproj_z0 fused (qproj blocks
//      first, latency-hidden by memory-bound transpose blocks); dead
//      standalone kernels removed. 8 launches (was 10). GEMM/PV cores
//      unchanged from R13 (TRIPLE variants).
// Workspace: 0 x1b, 8 x2b, 16 x4b | 24/32/40 x1t/x2t/x4t | 48 Wb |
//   52 Qs (4x8MB, F_a overlays Q_a) | 84 P0 (128MB) | 212 P1 (128MB)

#define DEV __device__ __forceinline__
typedef unsigned short u16;
typedef __bf16 bf16x8 __attribute__((ext_vector_type(8)));
typedef float f32x4 __attribute__((ext_vector_type(4)));

constexpr int NR = 8192;
constexpr int DDIM = 512;
constexpr int TOUT = 12;

DEV u16 f2b(float f) {
  uint32_t u = __builtin_bit_cast(uint32_t, f);
  u += 0x7fffu + ((u >> 16) & 1u);
  return (u16)(u >> 16);
}
DEV float b2f(u16 h) {
  uint32_t u = ((uint32_t)h) << 16;
  return __builtin_bit_cast(float, u);
}

// ---------------- prep: LayerNorm (blocks 0..6143) + Wconv (6144..6655) ----
__global__ __launch_bounds__(256) void prep_kernel(
    const float* __restrict__ xp, const float* __restrict__ xm,
    const float* __restrict__ xs, const float* __restrict__ g,
    const float* __restrict__ b, const float* __restrict__ W1,
    const float* __restrict__ W2, const float* __restrict__ W3,
    const float* __restrict__ W4, u16* __restrict__ o1, u16* __restrict__ o2,
    u16* __restrict__ o4, u16* __restrict__ Wb) {
  int bid = blockIdx.x;
  int tid = threadIdx.x;
  if (bid < 6144) {
    int which = bid >> 11;                       // 2048 blocks per matrix
    int row = ((bid & 2047) << 2) + (tid >> 6);  // 4 rows/block
    int lane = tid & 63;
    const float* x = which == 0 ? xp : (which == 1 ? xm : xs);
    u16* o = which == 0 ? o1 : (which == 1 ? o2 : o4);
    const float4* xr = (const float4*)(x + (size_t)row * DDIM);
    float4 v0 = xr[lane * 2], v1 = xr[lane * 2 + 1];
    float vals[8] = {v0.x, v0.y, v0.z, v0.w, v1.x, v1.y, v1.z, v1.w};
    float s = 0.f, s2 = 0.f;
    for (int j = 0; j < 8; j++) { s += vals[j]; s2 += vals[j] * vals[j]; }
    for (int off = 1; off < 64; off <<= 1) {
      s += __shfl_xor(s, off);
      s2 += __shfl_xor(s2, off);
    }
    float m = s * (1.0f / DDIM);
    float var = s2 * (1.0f / DDIM) - m * m;
    var = fmaxf(var, 0.f);
    float rs = rsqrtf(var + 1e-6f);
    int d0 = lane * 8;
    u16 us[8];
    for (int j = 0; j < 8; j++)
      us[j] = f2b((vals[j] - m) * rs * g[d0 + j] + b[d0 + j]);
    uint4 pk;
    pk.x = (uint32_t)us[0] | ((uint32_t)us[1] << 16);
    pk.y = (uint32_t)us[2] | ((uint32_t)us[3] << 16);
    pk.z = (uint32_t)us[4] | ((uint32_t)us[5] << 16);
    pk.w = (uint32_t)us[6] | ((uint32_t)us[7] << 16);
    *(uint4*)(o + (size_t)row * DDIM + d0) = pk;
  } else {
    int wbid = bid - 6144;
    int wi = wbid >> 7;  // 128 blocks per matrix
    const float* W = wi == 0 ? W1 : (wi == 1 ? W2 : (wi == 2 ? W3 : W4));
    size_t base = ((size_t)(wbid & 127) * 256 + tid) * 8;
    const float4* src = (const float4*)(W + base);
    float4 a = src[0], c = src[1];
    float vals[8] = {a.x, a.y, a.z, a.w, c.x, c.y, c.z, c.w};
    u16 us[8];
    for (int j = 0; j < 8; j++) us[j] = f2b(vals[j]);
    uint4 pk;
    pk.x = (uint32_t)us[0] | ((uint32_t)us[1] << 16);
    pk.y = (uint32_t)us[2] | ((uint32_t)us[3] << 16);
    pk.z = (uint32_t)us[4] | ((uint32_t)us[5] << 16);
    pk.w = (uint32_t)us[6] | ((uint32_t)us[7] << 16);
    *(uint4*)(Wb + (size_t)wi * DDIM * DDIM + base) = pk;
  }
}

// ---------------- shared bt-GEMM core (BM=BN=128, BK=32, 2x2 wave grid) ----
// TRIPLE=false: 2-buffer 2-barrier (R10), lds >= 16384 u16 (32 KB).
// TRIPLE=true:  3-buffer 1-barrier (R12), lds >= 24576 u16 (48 KB).
// LDS slot (row,s) holds global chunk (s-(row>>1))&3; reader uses
// s=(q+(r>>1))&3 -> bank-group (4r+s)%8 covers all 8 -> 2-way (free).
// MODE 0: out bf16 = acc + bias[col]   MODE 1: out bf16 = exp(acc - 48)
template <int MODE, bool TRIPLE>
DEV void gemm_core(const u16* __restrict__ A, const u16* __restrict__ B,
                   u16* __restrict__ C, const float* __restrict__ bias,
                   u16* lds, int K, int lda, int ldb, int ldc, int bx,
                   int by) {
  constexpr int TM = 4, TN = 4;
  int tid = threadIdx.x;
  int w = tid >> 6, lane = tid & 63;
  int q = lane >> 4, c16 = lane & 15;
  int n0 = bx * 128, m0 = by * 128;
  int wrow = (w >> 1) * 64, wcol = (w & 1) * 64;

  // hoisted staging pointers: this wave handles calls w, w+4, w+8, w+12
  const u16* gptr[4];
  int lof[4];  // u16 offset within a buffer (wave-uniform base)
#pragma unroll
  for (int j = 0; j < 4; j++) {
    int call = w + j * 4;
    bool isA = call < 8;
    int ci = isA ? call : call - 8;
    int chunk = ci * 64 + lane;
    int row = chunk >> 2;
    int gch = ((chunk & 3) - (row >> 1)) & 3;  // source chunk for this slot
    gptr[j] = isA ? (A + (size_t)(m0 + row) * lda + gch * 8)
                  : (B + (size_t)(n0 + row) * ldb + gch * 8);
    lof[j] = (isA ? 0 : 4096) + ci * 512;
  }
  auto stageAll = [&](int buf) {
    int bo = buf * 8192;
#pragma unroll
    for (int j = 0; j < 4; j++) {
      __builtin_amdgcn_global_load_lds(
          (const __attribute__((address_space(1))) void*)gptr[j],
          (__attribute__((address_space(3))) void*)(lds + bo + lof[j]), 16, 0,
          0);
      gptr[j] += 32;  // next K-step (32 u16 = 64 B)
    }
  };

  f32x4 acc[TM][TN] = {};
  int nk = K >> 5;  // 16 for K=512
  stageAll(0);
  stageAll(1);  // 8 loads in flight per wave
  int cur = 0;
  for (int ks = 0; ks < nk; ks++) {
    if (ks + 1 < nk)
      asm volatile("s_waitcnt vmcnt(4)" ::: "memory");
    else
      asm volatile("s_waitcnt vmcnt(0)" ::: "memory");
    __builtin_amdgcn_sched_barrier(0);
    __builtin_amdgcn_s_barrier();
    __builtin_amdgcn_sched_barrier(0);
    if constexpr (TRIPLE) {
      if (ks + 2 < nk) {
        int nb = cur + 2;
        if (nb >= 3) nb -= 3;
        stageAll(nb);  // tile ks+2 -> buf (ks+2)%3 (last read at ks-1)
      }
    }
    const u16* Asm = lds + cur * 8192;
    const u16* Bsm = Asm + 4096;
    bf16x8 af[TM], bfr[TN];
#pragma unroll
    for (int i = 0; i < TM; i++) {
      int r = wrow + i * 16 + c16;
      af[i] = *(const bf16x8*)&Asm[r * 32 + (((q + (r >> 1)) & 3) * 8)];
    }
#pragma unroll
    for (int n = 0; n < TN; n++) {
      int r = wcol + n * 16 + c16;
      bfr[n] = *(const bf16x8*)&Bsm[r * 32 + (((q + (r >> 1)) & 3) * 8)];
    }
    __builtin_amdgcn_s_setprio(1);
#pragma unroll
    for (int i = 0; i < TM; i++)
#pragma unroll
      for (int n = 0; n < TN; n++)
        acc[i][n] = __builtin_amdgcn_mfma_f32_16x16x32_bf16(af[i], bfr[n],
                                                            acc[i][n], 0, 0, 0);
    __builtin_amdgcn_s_setprio(0);
    if constexpr (!TRIPLE) {
      asm volatile("s_waitcnt lgkmcnt(0)" ::: "memory");
      __builtin_amdgcn_sched_barrier(0);
      __builtin_amdgcn_s_barrier();
      __builtin_amdgcn_sched_barrier(0);
      if (ks + 2 < nk) stageAll(cur);  // refill the buffer just consumed
      cur ^= 1;
    } else {
      cur++;
      if (cur >= 3) cur -= 3;
    }
  }
  // ---- coalesced epilogue: two passes over col-halves of the 128x128 tile --
  for (int h = 0; h < 2; h++) {
    __syncthreads();
    if ((w & 1) == h) {
      for (int i = 0; i < TM; i++) {
        for (int n = 0; n < TN; n++) {
          float bv = 0.f;
          if constexpr (MODE == 0) bv = bias[n0 + wcol + n * 16 + c16];
          for (int r = 0; r < 4; r++) {
            int rl = wrow + i * 16 + q * 4 + r;                // 0..127
            int cl = (n * 16 + c16) ^ ((rl & 7) << 3);         // swizzled col
            float v = acc[i][n][r];
            if constexpr (MODE == 0) v += bv;
            if constexpr (MODE == 1) v = __expf(v - 48.0f);
            lds[rl * 64 + cl] = f2b(v);
          }
        }
      }
    }
    __syncthreads();
    for (int rep = 0; rep < 4; rep++) {
      int idx = rep * 256 + tid;  // 0..1023 uint4s = 128 rows x 8 segs
      int row = idx >> 3, seg = idx & 7;
      uint4 vv = ((const uint4*)lds)[row * 8 + (seg ^ (row & 7))];
      *(uint4*)(C + (size_t)(m0 + row) * ldc + n0 + h * 64 + seg * 8) = vv;
    }
  }
}

// ---------------- tqp: qproj z=0 (blocks 0..255) + transpose (256..3327) ----
__global__ __launch_bounds__(256, 4) void tqp_kernel(
    const u16* __restrict__ s1, const u16* __restrict__ s2,
    const u16* __restrict__ s4, u16* __restrict__ t1, u16* __restrict__ t2,
    u16* __restrict__ t4, const u16* __restrict__ x1b,
    const u16* __restrict__ Wb, const float* __restrict__ b0,
    u16* __restrict__ Qs) {
  __shared__ u16 lds[16384];
  int bid = blockIdx.x;
  int tid = threadIdx.x;
  if (bid < 256) {
    gemm_core<0, false>(x1b, Wb, Qs, b0, lds, DDIM, DDIM, DDIM, DDIM,
                        bid & 3, bid >> 2);
  } else {
    constexpr int LD = 66;
    u16* tile = lds;  // 64*66 = 4224 u16 < 16384
    int tb = bid - 256;
    int which = tb >> 10;  // 1024 blocks per matrix (8 x 128)
    int rem = tb & 1023;
    int c0 = (rem & 7) * 64;
    int r0 = (rem >> 3) * 64;
    const u16* src = which == 0 ? s1 : (which == 1 ? s2 : s4);
    u16* dst = which == 0 ? t1 : (which == 1 ? t2 : t4);
    for (int c = tid; c < 512; c += 256) {
      int i = c >> 3, j8 = (c & 7) * 8;
      uint4 v = *(const uint4*)(src + (size_t)(r0 + i) * DDIM + c0 + j8);
      uint32_t* dw = (uint32_t*)&tile[i * LD + j8];
      dw[0] = v.x; dw[1] = v.y; dw[2] = v.z; dw[3] = v.w;
    }
    __syncthreads();
    for (int rep = 0; rep < 2; rep++) {
      int idx = rep * 256 + tid;
      int o = idx >> 3, j8 = (idx & 7) * 8;
      u16 us[8];
      for (int k = 0; k < 8; k++) us[k] = tile[(j8 + k) * LD + o];
      uint4 pk;
      pk.x = (uint32_t)us[0] | ((uint32_t)us[1] << 16);
      pk.y = (uint32_t)us[2] | ((uint32_t)us[3] << 16);
      pk.z = (uint32_t)us[4] | ((uint32_t)us[5] << 16);
      pk.w = (uint32_t)us[6] | ((uint32_t)us[7] << 16);
      *(uint4*)(dst + (size_t)(c0 + o) * NR + r0 + j8) = pk;
    }
  }
}

// ---------------- PV body: F = (P V)/(l sqrt512) ----------
// BM=64, BN=128, BK=64; 512 blocks. Counted-vmcnt 2-buffer pipeline (R10,
// proven). lds: 24576 u16 (48 KB): A dbuf [0,8192), B dbuf [8192,24576).
DEV void pv_body(const u16* __restrict__ A, const u16* __restrict__ B,
                 u16* lds, u16* __restrict__ C, int bx, int by) {
  constexpr int BM = 64, BN = 128, BK = 64;
  int tid = threadIdx.x, w = tid >> 6, lane = tid & 63;
  int q = lane >> 4, c16 = lane & 15;
  int n0 = bx * BN, m0 = by * BM;
  int wr = (w >> 1) * 32, wc = (w & 1) * 64;
  f32x4 acc[2][4] = {};
  f32x4 accl[2] = {};
  bf16x8 ones;
  for (int j = 0; j < 8; j++) ones[j] = (__bf16)1.0f;

  const u16* gptr[6];
  int lof0[6], lof1[6];
#pragma unroll
  for (int it = 0; it < 6; it++) {
    int cb = it * 256 + w * 64;  // wave-uniform
    int c = cb + lane;
    bool isA = cb < 512;  // uniform per wave
    int ci = isA ? c : c - 512;
    int row = ci >> 3;
    int koff = ((ci & 7) ^ (row & 7)) * 8;  // full 8-group swizzle
    gptr[it] = isA ? (A + (size_t)(m0 + row) * NR + koff)
                   : (B + (size_t)(n0 + row) * NR + koff);
    lof0[it] = isA ? (cb * 8) : (8192 + (cb - 512) * 8);
    lof1[it] = isA ? (4096 + cb * 8) : (16384 + (cb - 512) * 8);
  }
  auto stage = [&](int buf) {
#pragma unroll
    for (int it = 0; it < 6; it++) {
      int lo = buf ? lof1[it] : lof0[it];
      __builtin_amdgcn_global_load_lds(
          (const __attribute__((address_space(1))) void*)gptr[it],
          (__attribute__((address_space(3))) void*)(lds + lo), 16, 0, 0);
      gptr[it] += BK;  // next K-tile (64 u16 = 128 B)
    }
  };

  constexpr int KSTEPS = NR / BK;
  stage(0);
  stage(1);  // 12 loads in flight
  for (int ks = 0; ks < KSTEPS; ks++) {
    int cur = ks & 1;
    if (ks + 1 < KSTEPS)
      asm volatile("s_waitcnt vmcnt(6)" ::: "memory");
    else
      asm volatile("s_waitcnt vmcnt(0)" ::: "memory");
    __builtin_amdgcn_sched_barrier(0);
    __builtin_amdgcn_s_barrier();
    __builtin_amdgcn_sched_barrier(0);
    const u16* Asm = lds + cur * 4096;
    const u16* Bsm = lds + 8192 + cur * 8192;
#pragma unroll
    for (int kh = 0; kh < 2; kh++) {
      bf16x8 af[2], bfr[4];
      int cl = kh * 4 + q;
#pragma unroll
      for (int i = 0; i < 2; i++) {
        int r = wr + i * 16 + c16;
        af[i] = *(const bf16x8*)&Asm[r * BK + ((cl ^ (r & 7)) * 8)];
      }
#pragma unroll
      for (int n = 0; n < 4; n++) {
        int r = wc + n * 16 + c16;
        bfr[n] = *(const bf16x8*)&Bsm[r * BK + ((cl ^ (r & 7)) * 8)];
      }
      __builtin_amdgcn_s_setprio(1);
#pragma unroll
      for (int i = 0; i < 2; i++)
        accl[i] = __builtin_amdgcn_mfma_f32_16x16x32_bf16(af[i], ones, accl[i],
                                                          0, 0, 0);
#pragma unroll
      for (int i = 0; i < 2; i++)
#pragma unroll
        for (int n = 0; n < 4; n++)
          acc[i][n] = __builtin_amdgcn_mfma_f32_16x16x32_bf16(
              af[i], bfr[n], acc[i][n], 0, 0, 0);
      __builtin_amdgcn_s_setprio(0);
    }
    asm volatile("s_waitcnt lgkmcnt(0)" ::: "memory");
    __builtin_amdgcn_sched_barrier(0);
    __builtin_amdgcn_s_barrier();
    __builtin_amdgcn_sched_barrier(0);
    if (ks + 2 < KSTEPS) stage(cur);  // refill freed buffer
  }
  for (int i = 0; i < 2; i++) {
    float invl[4];
    for (int r = 0; r < 4; r++)
      invl[r] = 0.044194173824159216f / accl[i][r];  // 1/(l*sqrt(512))
    for (int n = 0; n < 4; n++) {
      int col = n0 + wc + n * 16 + c16;
      for (int r = 0; r < 4; r++) {
        int row = m0 + wr + i * 16 + q * 4 + r;
        C[(size_t)row * DDIM + col] = f2b(acc[i][n][r] * invl[r]);
      }
    }
  }
}

// XCD-grouping remap for pv blocks (bid in 0..511): the 4 blocks sharing a
// by (and its 1MB P-panel) get bids congruent mod 8 -> same XCD L2.
DEV void pv_remap(int bid, int& bx, int& by) {
  bx = (bid >> 3) & 3;
  by = (bid & 7) + 8 * (bid >> 5);
}

// scores: P = exp(Q K^T - 48)   grid (64,64)  (fallback path only)
__global__ __launch_bounds__(256, 4) void scores_kernel(
    const u16* __restrict__ Q, const u16* __restrict__ Kv,
    u16* __restrict__ P) {
  __shared__ u16 lds[16384];
  gemm_core<1, false>(Q, Kv, P, nullptr, lds, DDIM, DDIM, DDIM, NR,
                      blockIdx.x, blockIdx.y);
}

// qscombo: blocks 0..767 -> qproj z=1..3; blocks 768.. -> scores_0
__global__ __launch_bounds__(256, 4) void qscombo_kernel(
    const u16* __restrict__ x1b, const u16* __restrict__ x2b,
    const u16* __restrict__ x4b, const u16* __restrict__ Wb,
    const float* __restrict__ b1, const float* __restrict__ b2,
    const float* __restrict__ b3, u16* __restrict__ Qs,
    const u16* __restrict__ Q0, u16* __restrict__ P) {
  __shared__ u16 lds[16384];
  if (blockIdx.x < 768) {
    int b = blockIdx.x;
    int z = 1 + (b >> 8), rem = b & 255;
    const u16* A = z == 1 ? x2b : (z == 2 ? x1b : x4b);
    const float* bias = z == 1 ? b1 : (z == 2 ? b2 : b3);
    gemm_core<0, false>(A, Wb + (size_t)z * DDIM * DDIM,
                        Qs + (size_t)z * NR * DDIM, bias, lds, DDIM, DDIM,
                        DDIM, DDIM, rem & 3, rem >> 2);
  } else {
    int b = blockIdx.x - 768;
    gemm_core<1, false>(Q0, x2b, P, nullptr, lds, DDIM, DDIM, DDIM, NR,
                        b & 63, b >> 6);
  }
}

// standalone PV   grid (512)
__global__ __launch_bounds__(256, 3) void pv_kernel(
    const u16* __restrict__ A, const u16* __restrict__ B,
    u16* __restrict__ C) {
  __shared__ u16 lds[24576];
  int bx, by;
  pv_remap(blockIdx.x, bx, by);
  pv_body(A, B, lds, C, bx, by);
}

// combo: blocks 0..511 -> pv_a (Pin->F); blocks 512.. -> scores_{a+1}
__global__ __launch_bounds__(256, 3) void combo_kernel(
    const u16* __restrict__ Pin, const u16* __restrict__ Vt,
    u16* __restrict__ F, const u16* __restrict__ Q,
    const u16* __restrict__ Kv, u16* __restrict__ Pout) {
  __shared__ u16 lds[24576];
  if (blockIdx.x < 512) {
    int bx, by;
    pv_remap(blockIdx.x, bx, by);
    pv_body(Pin, Vt, lds, F, bx, by);
  } else {
    int b = blockIdx.x - 512;
    gemm_core<1, true>(Q, Kv, Pout, nullptr, lds, DDIM, DDIM, DDIM, NR,
                       b & 63, b >> 6);
  }
}

// ---------------- fused head: concat+relu+Wp+bias+gate ----------------
__global__ __launch_bounds__(256) void head_kernel(
    const u16* __restrict__ F1, const u16* __restrict__ F2,
    const u16* __restrict__ F3, const u16* __restrict__ F4,
    const u16* __restrict__ x1, const u16* __restrict__ x2,
    const u16* __restrict__ x4, const float* __restrict__ Wp,
    const float* __restrict__ bp, const float* __restrict__ tg,
    const float* __restrict__ Wt1, const float* __restrict__ bt1,
    const float* __restrict__ Wt2, const float* __restrict__ bt2,
    float* __restrict__ out) {
  __shared__ float wps[TOUT * 2 * DDIM];
  __shared__ float t2s;
  int tid = threadIdx.x;
  for (int i = tid; i < TOUT * 2 * DDIM; i += 256) wps[i] = Wp[i];
  if (tid == 0) {
    float s = bt2[0];
    for (int k = 0; k < 50; k++) s += Wt2[k] * (tg[0] * Wt1[k] + bt1[k]);
    t2s = 1.0f / (1.0f + __expf(-s));
  }
  __syncthreads();
  int g = tid >> 5, j = tid & 31;
  size_t m = (size_t)blockIdx.x * 8 + g;
  float a12[TOUT] = {}, a34[TOUT] = {};
  for (int d = j; d < 2 * DDIM; d += 32) {
    float h12, h34;
    if (d < DDIM) {
      float xv = b2f(x1[m * DDIM + d]);
      h12 = b2f(F1[m * DDIM + d]) + xv;
      h34 = b2f(F3[m * DDIM + d]) + xv;
    } else {
      int dd = d - DDIM;
      h12 = b2f(F2[m * DDIM + dd]) + b2f(x2[m * DDIM + dd]);
      h34 = b2f(F4[m * DDIM + dd]) + b2f(x4[m * DDIM + dd]);
    }
    h12 = fmaxf(h12, 0.f);
    h34 = fmaxf(h34, 0.f);
    for (int t = 0; t < TOUT; t++) {
      float wv = wps[t * 2 * DDIM + d];
      a12[t] += h12 * wv;
      a34[t] += h34 * wv;
    }
  }
  for (int off = 1; off < 32; off <<= 1)
    for (int t = 0; t < TOUT; t++) {
      a12[t] += __shfl_xor(a12[t], off);
      a34[t] += __shfl_xor(a34[t], off);
    }
  if (j < TOUT) {
    float t2 = t2s;
    out[m * TOUT + j] = t2 * a12[j] + (1.f - t2) * a34[j] + bp[j];
  }
}

extern "C" void kernel_launch(void* const* d_in, const int* in_sizes, int n_in,
                              void* d_out, int out_size, void* d_ws,
                              size_t ws_size, hipStream_t stream) {
  (void)in_sizes; (void)n_in; (void)out_size;
  const float* xp = (const float*)d_in[0];
  const float* xm = (const float*)d_in[1];
  const float* xs = (const float*)d_in[2];
  const float* ln_g = (const float*)d_in[3];
  const float* ln_b = (const float*)d_in[4];
  const float* Wmat[4] = {(const float*)d_in[5], (const float*)d_in[7],
                          (const float*)d_in[9], (const float*)d_in[11]};
  const float* bvec[4] = {(const float*)d_in[6], (const float*)d_in[8],
                          (const float*)d_in[10], (const float*)d_in[12]};
  const float* Wp = (const float*)d_in[13];
  const float* bp = (const float*)d_in[14];
  const float* tg = (const float*)d_in[15];
  const float* Wt1 = (const float*)d_in[16];
  const float* bt1 = (const float*)d_in[17];
  const float* Wt2 = (const float*)d_in[18];
  const float* bt2 = (const float*)d_in[19];
  float* out = (float*)d_out;

  char* ws = (char*)d_ws;
  const size_t MB = 1ull << 20;
  u16* x1b = (u16*)(ws + 0 * MB);
  u16* x2b = (u16*)(ws + 8 * MB);
  u16* x4b = (u16*)(ws + 16 * MB);
  u16* x1t = (u16*)(ws + 24 * MB);
  u16* x2t = (u16*)(ws + 32 * MB);
  u16* x4t = (u16*)(ws + 40 * MB);
  u16* Wb = (u16*)(ws + 48 * MB);
  u16* Qs = (u16*)(ws + 52 * MB);  // 4 slots of 8 MB; F_a overlays Q_a
  u16* P0 = (u16*)(ws + 84 * MB);  // 128 MiB
  bool dual = ws_size >= 340 * MB;
  u16* P1 = dual ? (u16*)(ws + 212 * MB) : P0;

  // ln (6144) + wconv (512)
  prep_kernel<<<dim3(6656), 256, 0, stream>>>(
      xp, xm, xs, ln_g, ln_b, Wmat[0], Wmat[1], Wmat[2], Wmat[3], x1b, x2b,
      x4b, Wb);

  const u16* kvb[4] = {x2b, x1b, x4b, x1b};
  const u16* kvt[4] = {x2t, x1t, x4t, x1t};
  u16* slot[4];
  for (int a = 0; a < 4; a++) slot[a] = Qs + (size_t)a * NR * DDIM;

  // qproj z=0 (256, first for early schedule) + transpose x3 (3072)
  tqp_kernel<<<dim3(3328), 256, 0, stream>>>(x1b, x2b, x4b, x1t, x2t, x4t,
                                             x1b, Wb, bvec[0], Qs);

  // qproj z=1..3 packed with scores_0
  qscombo_kernel<<<dim3(768 + 64 * 64), 256, 0, stream>>>(
      x1b, x2b, x4b, Wb, bvec[1], bvec[2], bvec[3], Qs, slot[0], P0);

  if (dual) {
    u16* Pb[4] = {P0, P1, P0, P1};
    for (int a = 0; a < 3; a++) {
      // pv_a (P_a -> F_a over Q_a) || scores_{a+1} (-> other P buffer)
      combo_kernel<<<dim3(512 + 64 * 64), 256, 0, stream>>>(
          Pb[a], kvt[a], slot[a], slot[a + 1], kvb[a + 1], Pb[a + 1]);
    }
    pv_kernel<<<dim3(512), 256, 0, stream>>>(Pb[3], kvt[3], slot[3]);
  } else {
    for (int a = 0; a < 4; a++) {
      if (a > 0)
        scores_kernel<<<dim3(64, 64), 256, 0, stream>>>(slot[a], kvb[a], P0);
      pv_kernel<<<dim3(512), 256, 0, stream>>>(P0, kvt[a], slot[a]);
    }
  }

  // attention a -> f[fidx[a]]: a0->f2, a1->f1, a2->f4, a3->f3
  head_kernel<<<dim3(NR / 8), 256, 0, stream>>>(
      slot[1], slot[0], slot[3], slot[2], x1b, x2b, x4b, Wp, bp, tg, Wt1, bt1,
      Wt2, bt2, out);
}